// Round 11
// baseline (4867.682 us; speedup 1.0000x reference)
//
#include <hip/hip_runtime.h>

#define L_SEQ 1024
#define B_SZ  16
#define D_SZ  512
#define V_SZ  10000
#define HQ_DEPTH 32    // h ring (32 KB/slot); gh skew <=1, gxp lag << 30
#define REC_DEPTH 64   // record ring; consumer lag << 62
#define WSTR 536       // wlds row stride in u16: 268 words % 32 = 12 -> 2-way (free)
#define PW_T 272       // pscr tile stride in f32 (16 rows x 17)
#define PW_WAVE 1632   // 6 tiles x 272
#define PW_BUF 6528    // 4 waves x 1632

typedef __attribute__((ext_vector_type(8))) short bf16x8;
typedef __attribute__((ext_vector_type(4))) float f32x4;
typedef __attribute__((ext_vector_type(4))) unsigned int u32x4;
typedef __attribute__((ext_vector_type(2))) unsigned int u32x2;

__device__ __forceinline__ float bf2f(unsigned int u) {
  unsigned int x = (u & 0xffffu) << 16;
  return __builtin_bit_cast(float, x);
}
__device__ __forceinline__ unsigned short f2bf(float f) {
  unsigned int x = __builtin_bit_cast(unsigned int, f);
  x += 0x7fffu + ((x >> 16) & 1u);
  return (unsigned short)(x >> 16);
}
__device__ __forceinline__ unsigned int pk2(float lo, float hi) {
  return (unsigned int)f2bf(lo) | ((unsigned int)f2bf(hi) << 16);
}
__device__ __forceinline__ float sigm(float x) { return 1.f / (1.f + __expf(-x)); }
__device__ __forceinline__ float tanhfast(float x) {
  x = fminf(fmaxf(x, -15.f), 15.f);
  float e = __expf(2.f * x);
  return (e - 1.f) / (e + 1.f);
}

#define KPAD 40

// ---------------- K1: gi = gather(emb, tokens) @ W_ih^T + b_ih ----------------
__global__ __launch_bounds__(256) void k_gi(
    const int* __restrict__ tokens, const float* __restrict__ emb,
    const float* __restrict__ Wih, const float* __restrict__ bih,
    unsigned short* __restrict__ giT)
{
  __shared__ unsigned short As[64 * KPAD];
  __shared__ unsigned short Bs[64 * KPAD];
  const int tid = threadIdx.x, lane = tid & 63, wv = tid >> 6;
  const int m0 = blockIdx.y * 64, n0 = blockIdx.x * 64;
  const int sr = tid >> 2, skc = (tid & 3) * 8;
  const int grow = m0 + sr;
  const int tok = tokens[((grow & 15) << 10) + (grow >> 4)];
  const float* asrc = emb + (size_t)tok * 512 + skc;
  const float* bsrc = Wih + (size_t)(n0 + sr) * 512 + skc;

  f32x4 acc[4];
  #pragma unroll
  for (int i = 0; i < 4; ++i) acc[i] = 0.f;

  for (int ks = 0; ks < 16; ++ks) {
    __syncthreads();
    float4 a0 = *(const float4*)(asrc + ks * 32);
    float4 a1 = *(const float4*)(asrc + ks * 32 + 4);
    float4 q0 = *(const float4*)(bsrc + ks * 32);
    float4 q1 = *(const float4*)(bsrc + ks * 32 + 4);
    uint4 ua = { pk2(a0.x, a0.y), pk2(a0.z, a0.w), pk2(a1.x, a1.y), pk2(a1.z, a1.w) };
    uint4 ub = { pk2(q0.x, q0.y), pk2(q0.z, q0.w), pk2(q1.x, q1.y), pk2(q1.z, q1.w) };
    *(uint4*)&As[sr * KPAD + skc] = ua;
    *(uint4*)&Bs[sr * KPAD + skc] = ub;
    __syncthreads();
    bf16x8 af = *(const bf16x8*)&As[(wv * 16 + (lane & 15)) * KPAD + (lane >> 4) * 8];
    #pragma unroll
    for (int ns = 0; ns < 4; ++ns) {
      bf16x8 bfv = *(const bf16x8*)&Bs[(ns * 16 + (lane & 15)) * KPAD + (lane >> 4) * 8];
      acc[ns] = __builtin_amdgcn_mfma_f32_16x16x32_bf16(af, bfv, acc[ns], 0, 0, 0);
    }
  }
  const int mrow = m0 + wv * 16 + 4 * (lane >> 4);
  const int ncol = n0 + (lane & 15);
  #pragma unroll
  for (int ns = 0; ns < 4; ++ns) {
    int col = ncol + ns * 16;
    float bv = bih[col];
    #pragma unroll
    for (int rr = 0; rr < 4; ++rr) {
      int row = mrow + rr;
      giT[((size_t)(row >> 4) * 1536 + col) * 16 + (row & 15)] = f2bf(acc[ns][rr] + bv);
    }
  }
}

#define ISSUE_BATCH(R0,R1,R2,R3,R4,R5,R6,R7,PTR)                       \
  asm volatile(                                                        \
    "global_load_dwordx4 %0, %8, off sc0 sc1\n\t"                      \
    "global_load_dwordx4 %1, %8, off offset:16 sc0 sc1\n\t"            \
    "global_load_dwordx4 %2, %8, off offset:128 sc0 sc1\n\t"           \
    "global_load_dwordx4 %3, %8, off offset:144 sc0 sc1\n\t"           \
    "global_load_dwordx4 %4, %8, off offset:256 sc0 sc1\n\t"           \
    "global_load_dwordx4 %5, %8, off offset:272 sc0 sc1\n\t"           \
    "global_load_dwordx4 %6, %8, off offset:384 sc0 sc1\n\t"           \
    "global_load_dwordx4 %7, %8, off offset:400 sc0 sc1"               \
    : "=&v"(R0), "=&v"(R1), "=&v"(R2), "=&v"(R3),                      \
      "=&v"(R4), "=&v"(R5), "=&v"(R6), "=&v"(R7)                       \
    : "v"(PTR) : "memory")

#define TAGS_OK(R0,R1,R2,R3,R4,R5,R6,R7,TV)                            \
  ((R0.y == TV) & (R0.w == TV) & (R1.y == TV) & (R1.w == TV) &         \
   (R2.y == TV) & (R2.w == TV) & (R3.y == TV) & (R3.w == TV) &         \
   (R4.y == TV) & (R4.w == TV) & (R5.y == TV) & (R5.w == TV) &         \
   (R6.y == TV) & (R6.w == TV) & (R7.y == TV) & (R7.w == TV))

// ---------------- K2: persistent fused scan, K-split tagged exchange ----------------
// R10 base (3.25ms). New: gh waves PRE-ISSUE next step's poll batch right after
// the h publish atomic. In-flight at next check = [pub(1), preA(8), gi(6)] oldest
// first, so vmcnt(6) drains exactly pub+preA (never fresh ops). Tag check on the
// pre-batch: hit -> zero fallback polling; miss (stale tags, always detectable)
// -> R10's vmcnt(0) fallback loop.
__global__ __launch_bounds__(256) void k_scan(
    const unsigned short* __restrict__ giT,
    const float* __restrict__ Whh, const float* __restrict__ bhh,
    const float* __restrict__ Wg, const float* __restrict__ bg,
    const float* __restrict__ Wx, const float* __restrict__ bx,
    const float* __restrict__ Wp, const float* __restrict__ bp,
    u32x4* __restrict__ recS, unsigned short* __restrict__ xhat,
    unsigned long long* __restrict__ hq)
{
  __shared__ char smem[155136];
  const int tid = threadIdx.x;
  const int lane = tid & 63, v = tid >> 6;
  const int wid = blockIdx.x;

  if (wid < 24) {
    const bool isGH = (wid < 16);
    const int w = isGH ? wid : (wid - 16);
    unsigned short* wlds = (unsigned short*)smem;   // 96 x 536 u16 = 102912 B
    float* pscr = (float*)(smem + 102912);          // 2 bufs x 4 waves x 6 x 272 f32

    for (int row = v; row < 96; row += 4) {
      const float* src;
      if (isGH) {
        src = Whh + ((size_t)(row >> 5) * 512 + w * 32 + (row & 31)) * 512;
      } else {
        int m = row >> 5;
        const float* Wm = (m == 0) ? Wg : (m == 1) ? Wx : Wp;
        src = Wm + (size_t)(w * 32 + (row & 31)) * 512;
      }
      float4 p0 = *(const float4*)(src + lane * 8);
      float4 p1 = *(const float4*)(src + lane * 8 + 4);
      uint4 uu = { pk2(p0.x, p0.y), pk2(p0.z, p0.w), pk2(p1.x, p1.y), pk2(p1.z, p1.w) };
      *(uint4*)&wlds[row * WSTR + lane * 8] = uu;
    }
    __syncthreads();

    const int b_ = lane & 15, hi = lane >> 4;
    const int bbh = tid & 15, dph = tid >> 4;   // gh pointwise mapping
    const int bbx = tid >> 4, dpx = tid & 15;   // gxp pointwise mapping

    float bhr1 = 0, bhz1 = 0, bhn1 = 0, bhr2 = 0, bhz2 = 0, bhn2 = 0;
    float bgc0 = 0, bgc1 = 0, bxc0 = 0, bxc1 = 0, bpc0 = 0, bpc1 = 0;
    float hprev1 = 0.f, hprev2 = 0.f;
    if (isGH) {
      int d0 = w * 32 + 2 * dph, d1 = d0 + 1;
      bhr1 = bhh[d0]; bhz1 = bhh[512 + d0]; bhn1 = bhh[1024 + d0];
      bhr2 = bhh[d1]; bhz2 = bhh[512 + d1]; bhn2 = bhh[1024 + d1];
    } else {
      int d0 = w * 32 + 2 * dpx, d1 = d0 + 1;
      bgc0 = bg[d0]; bgc1 = bg[d1];
      bxc0 = bx[d0]; bxc1 = bx[d1];
      bpc0 = bp[d0]; bpc1 = bp[d1];
    }

    float gir1 = 0, giz1 = 0, gin1 = 0, gir2 = 0, giz2 = 0, gin2 = 0;
    if (isGH) {
      int d0 = w * 32 + 2 * dph, d1 = d0 + 1;
      const unsigned short* gib = giT + bbh;
      gir1 = bf2f(gib[(size_t)d0 * 16]);
      giz1 = bf2f(gib[(size_t)(512 + d0) * 16]);
      gin1 = bf2f(gib[(size_t)(1024 + d0) * 16]);
      gir2 = bf2f(gib[(size_t)d1 * 16]);
      giz2 = bf2f(gib[(size_t)(512 + d1) * 16]);
      gin2 = bf2f(gib[(size_t)(1024 + d1) * 16]);
    }

    // B-fragment base for this wave's K-quarter (kk = 4v..4v+3)
    const unsigned short* bqbase = wlds + (size_t)b_ * WSTR + (size_t)(4 * v) * 32 + hi * 8;
    // per-lane poll address offset (constant across steps except the slot)
    const size_t pofs = (size_t)b_ * 256 + 64 * v + 4 * hi;

    // persistent pre-issued poll batch registers
    u32x4 pA0 = 0, pA1 = 0, pA2 = 0, pA3 = 0, pA4 = 0, pA5 = 0, pA6 = 0, pA7 = 0;

    #pragma unroll 1
    for (int t = 0; t < L_SEQ; ++t) {
      const int pt = isGH ? (t - 1) : t;   // h step consumed this iteration
      f32x4 pacc[6];
      #pragma unroll
      for (int i = 0; i < 6; ++i) pacc[i] = 0.f;

      if (pt >= 0) {
        const unsigned long long* hsrc = hq + (size_t)(pt & (HQ_DEPTH - 1)) * 4096 + pofs;
        const unsigned int tv = (unsigned int)(pt + 1);
        u32x4 s0, s1, s2, s3, s4, s5, s6, s7;
        bool hit = false;
        if (isGH && t >= 1) {
          // in-flight (oldest->newest): pub(1), preA(8), gi(6) => vmcnt(6)
          // completes exactly pub+preA. gi stays pending (compiler waits later).
          asm volatile("s_waitcnt vmcnt(6)" ::: "memory");
          __builtin_amdgcn_sched_barrier(0);
          if (__all(TAGS_OK(pA0, pA1, pA2, pA3, pA4, pA5, pA6, pA7, tv))) {
            s0 = pA0; s1 = pA1; s2 = pA2; s3 = pA3;
            s4 = pA4; s5 = pA5; s6 = pA6; s7 = pA7;
            hit = true;
          }
        }
        if (!hit) {
          u32x4 q0, q1, q2, q3, q4, q5, q6, q7;
          int spins = 0;
          for (;;) {
            ISSUE_BATCH(q0, q1, q2, q3, q4, q5, q6, q7, hsrc);
            asm volatile("s_waitcnt vmcnt(0)" ::: "memory");
            if (__all(TAGS_OK(q0, q1, q2, q3, q4, q5, q6, q7, tv))) break;
            if (!isGH) __builtin_amdgcn_s_sleep(4);
            if (++spins > 2000000) break;
          }
          s0 = q0; s1 = q1; s2 = q2; s3 = q3;
          s4 = q4; s5 = q5; s6 = q6; s7 = q7;
        }
        u32x4 f0 = { s0.x, s0.z, s1.x, s1.z };
        u32x4 f1 = { s2.x, s2.z, s3.x, s3.z };
        u32x4 f2 = { s4.x, s4.z, s5.x, s5.z };
        u32x4 f3 = { s6.x, s6.z, s7.x, s7.z };
        bf16x8 a0 = __builtin_bit_cast(bf16x8, f0);
        bf16x8 a1 = __builtin_bit_cast(bf16x8, f1);
        bf16x8 a2 = __builtin_bit_cast(bf16x8, f2);
        bf16x8 a3 = __builtin_bit_cast(bf16x8, f3);
        #pragma unroll
        for (int T = 0; T < 6; ++T) {
          const unsigned short* bp0 = bqbase + (size_t)T * (16 * WSTR);
          bf16x8 w0 = *(const bf16x8*)(bp0);
          bf16x8 w1 = *(const bf16x8*)(bp0 + 32);
          bf16x8 w2 = *(const bf16x8*)(bp0 + 64);
          bf16x8 w3 = *(const bf16x8*)(bp0 + 96);
          pacc[T] = __builtin_amdgcn_mfma_f32_16x16x32_bf16(a0, w0, pacc[T], 0, 0, 0);
          pacc[T] = __builtin_amdgcn_mfma_f32_16x16x32_bf16(a1, w1, pacc[T], 0, 0, 0);
          pacc[T] = __builtin_amdgcn_mfma_f32_16x16x32_bf16(a2, w2, pacc[T], 0, 0, 0);
          pacc[T] = __builtin_amdgcn_mfma_f32_16x16x32_bf16(a3, w3, pacc[T], 0, 0, 0);
        }
      }

      {
        float* pw = pscr + (size_t)(t & 1) * PW_BUF + (size_t)v * PW_WAVE;
        #pragma unroll
        for (int T = 0; T < 6; ++T) {
          #pragma unroll
          for (int rr = 0; rr < 4; ++rr)
            pw[T * PW_T + (4 * hi + rr) * 17 + b_] = pacc[T][rr];
        }
      }
      __syncthreads();   // nothing fresh in flight here (poll drained; pub/gi old)

      const float* pb = pscr + (size_t)(t & 1) * PW_BUF;
      if (isGH) {
        const int Tr = dph >> 3, j0 = (2 * dph) & 15;
        const int base0 = Tr * PW_T + bbh * 17 + j0;
        float ar1 = pb[base0]              + pb[PW_WAVE + base0]              + pb[2*PW_WAVE + base0]              + pb[3*PW_WAVE + base0];
        float ar2 = pb[base0 + 1]          + pb[PW_WAVE + base0 + 1]          + pb[2*PW_WAVE + base0 + 1]          + pb[3*PW_WAVE + base0 + 1];
        float az1 = pb[base0 + 2*PW_T]     + pb[PW_WAVE + base0 + 2*PW_T]     + pb[2*PW_WAVE + base0 + 2*PW_T]     + pb[3*PW_WAVE + base0 + 2*PW_T];
        float az2 = pb[base0 + 2*PW_T + 1] + pb[PW_WAVE + base0 + 2*PW_T + 1] + pb[2*PW_WAVE + base0 + 2*PW_T + 1] + pb[3*PW_WAVE + base0 + 2*PW_T + 1];
        float an1 = pb[base0 + 4*PW_T]     + pb[PW_WAVE + base0 + 4*PW_T]     + pb[2*PW_WAVE + base0 + 4*PW_T]     + pb[3*PW_WAVE + base0 + 4*PW_T];
        float an2 = pb[base0 + 4*PW_T + 1] + pb[PW_WAVE + base0 + 4*PW_T + 1] + pb[2*PW_WAVE + base0 + 4*PW_T + 1] + pb[3*PW_WAVE + base0 + 4*PW_T + 1];
        float r1 = sigm(ar1 + gir1 + bhr1);
        float z1 = sigm(az1 + giz1 + bhz1);
        float n1 = tanhfast(gin1 + r1 * (an1 + bhn1));
        float h1 = (1.f - z1) * n1 + z1 * hprev1; hprev1 = h1;
        float r2 = sigm(ar2 + gir2 + bhr2);
        float z2 = sigm(az2 + giz2 + bhz2);
        float n2 = tanhfast(gin2 + r2 * (an2 + bhn2));
        float h2 = (1.f - z2) * n2 + z2 * hprev2; hprev2 = h2;
        // h publish: fire-and-forget atomic (performed AT the LLC)
        u32x2 hv = { pk2(h1, h2), (unsigned int)(t + 1) };
        unsigned long long* hdst = hq + (size_t)(t & (HQ_DEPTH - 1)) * 4096
                                      + (size_t)bbh * 256 + w * 16 + dph;
        asm volatile("global_atomic_swap_x2 %0, %1, off sc1"
                     :: "v"(hdst), "v"(hv) : "memory");
        // PRE-ISSUE next step's poll batch (samples LLC ~when peers' atomics land)
        if (t + 1 < L_SEQ) {
          const unsigned long long* hn = hq + (size_t)(t & (HQ_DEPTH - 1)) * 4096 + pofs;
          ISSUE_BATCH(pA0, pA1, pA2, pA3, pA4, pA5, pA6, pA7, hn);
        }
        // gi(t+1) prefetch at tail (after preA: keeps preA older in vmcnt order)
        if (t + 1 < L_SEQ) {
          int d0 = w * 32 + 2 * dph, d1 = d0 + 1;
          const unsigned short* gib = giT + (size_t)(t + 1) * 1536 * 16 + bbh;
          gir1 = bf2f(gib[(size_t)d0 * 16]);
          giz1 = bf2f(gib[(size_t)(512 + d0) * 16]);
          gin1 = bf2f(gib[(size_t)(1024 + d0) * 16]);
          gir2 = bf2f(gib[(size_t)d1 * 16]);
          giz2 = bf2f(gib[(size_t)(512 + d1) * 16]);
          gin2 = bf2f(gib[(size_t)(1024 + d1) * 16]);
        }
      } else {
        const int Tg = dpx >> 3, j0 = (2 * dpx) & 15;
        const int base0 = Tg * PW_T + bbx * 17 + j0;
        float g0 = pb[base0]              + pb[PW_WAVE + base0]              + pb[2*PW_WAVE + base0]              + pb[3*PW_WAVE + base0];
        float g1 = pb[base0 + 1]          + pb[PW_WAVE + base0 + 1]          + pb[2*PW_WAVE + base0 + 1]          + pb[3*PW_WAVE + base0 + 1];
        float x0 = pb[base0 + 2*PW_T]     + pb[PW_WAVE + base0 + 2*PW_T]     + pb[2*PW_WAVE + base0 + 2*PW_T]     + pb[3*PW_WAVE + base0 + 2*PW_T];
        float x1 = pb[base0 + 2*PW_T + 1] + pb[PW_WAVE + base0 + 2*PW_T + 1] + pb[2*PW_WAVE + base0 + 2*PW_T + 1] + pb[3*PW_WAVE + base0 + 2*PW_T + 1];
        float p0 = pb[base0 + 4*PW_T]     + pb[PW_WAVE + base0 + 4*PW_T]     + pb[2*PW_WAVE + base0 + 4*PW_T]     + pb[3*PW_WAVE + base0 + 4*PW_T];
        float p1 = pb[base0 + 4*PW_T + 1] + pb[PW_WAVE + base0 + 4*PW_T + 1] + pb[2*PW_WAVE + base0 + 4*PW_T + 1] + pb[3*PW_WAVE + base0 + 4*PW_T + 1];
        g0 += bgc0; g1 += bgc1; x0 += bxc0; x1 += bxc1; p0 += bpc0; p1 += bpc1;
        u32x4 rec = { pk2(g0, g1), pk2(x0, x1), pk2(p0, p1), (unsigned int)(t + 1) };
        u32x4* rdst = recS + ((size_t)(t & (REC_DEPTH - 1)) * 16 + bbx) * 128 + w * 16 + dpx;
        asm volatile("global_store_dwordx4 %0, %1, off sc0 sc1" :: "v"(rdst), "v"(rec) : "memory");
      }
    }
  } else {
    // ---- consumers: 32 blocks x 4 independent waves = 128 M-slices ----
    const int id = wid - 24;            // 0..31
    const int b = id >> 1, sg = id & 1;
    const int sl = sg * 4 + v;          // slice 0..7 (32 cols each)
    float* Msh = (float*)(smem + v * 32768);  // [256][32] f32
    const int colg = lane & 7, dgs = lane >> 3;
    for (int i = lane * 4; i < 8192; i += 256) *(float4*)&Msh[i] = float4{0.f, 0.f, 0.f, 0.f};
    #pragma unroll 1
    for (int t = 0; t < L_SEQ; ++t) {
      const u32x4* rp = recS + ((size_t)(t & (REC_DEPTH - 1)) * 16 + b) * 128 + 2 * lane;
      const unsigned int tagv = (unsigned int)(t + 1);
      u32x4 r0, r1;
      int spins = 0;
      for (;;) {
        asm volatile(
          "global_load_dwordx4 %0, %2, off sc0 sc1\n\t"
          "global_load_dwordx4 %1, %2, off offset:16 sc0 sc1\n\t"
          "s_waitcnt vmcnt(0)"
          : "=&v"(r0), "=&v"(r1) : "v"(rp) : "memory");
        if (__all((r0.w == tagv) && (r1.w == tagv))) break;
        __builtin_amdgcn_s_sleep(8);   // consumers have huge slack; be polite
        if (++spins > 2000000) break;
      }
      const int lx = sl * 8 + colg;
      unsigned int xa = (unsigned int)__shfl((int)r0.y, lx);
      unsigned int xb = (unsigned int)__shfl((int)r1.y, lx);
      unsigned int pa = (unsigned int)__shfl((int)r0.z, lx);
      unsigned int pb2 = (unsigned int)__shfl((int)r1.z, lx);
      float xv0 = bf2f(xa), xv1 = bf2f(xa >> 16), xv2 = bf2f(xb), xv3 = bf2f(xb >> 16);
      float r0a = 0, r1a = 0, r2a = 0, r3a = 0;
      #pragma unroll
      for (int ic = 0; ic < 8; ++ic) {
        const int ls = dgs * 8 + ic;
        unsigned int ga = (unsigned int)__shfl((int)r0.x, ls);
        unsigned int gb = (unsigned int)__shfl((int)r1.x, ls);
        float gj[4] = { bf2f(ga), bf2f(ga >> 16), bf2f(gb), bf2f(gb >> 16) };
        int dg = dgs * 32 + ic * 4;
        #pragma unroll
        for (int j = 0; j < 4; ++j) {
          float4* mp = (float4*)&Msh[(dg + j) * 32 + colg * 4];
          float4 m = *mp;
          r0a += gj[j] * m.x; r1a += gj[j] * m.y; r2a += gj[j] * m.z; r3a += gj[j] * m.w;
          m.x += gj[j] * xv0; m.y += gj[j] * xv1; m.z += gj[j] * xv2; m.w += gj[j] * xv3;
          *mp = m;
        }
      }
      #pragma unroll
      for (int off = 8; off < 64; off <<= 1) {
        r0a += __shfl_xor(r0a, off); r1a += __shfl_xor(r1a, off);
        r2a += __shfl_xor(r2a, off); r3a += __shfl_xor(r3a, off);
      }
      if (dgs == 0) {
        float y0 = 0.5f * bf2f(pa) + 0.5f * r0a;
        float y1 = 0.5f * bf2f(pa >> 16) + 0.5f * r1a;
        float y2 = 0.5f * bf2f(pb2) + 0.5f * r2a;
        float y3 = 0.5f * bf2f(pb2 >> 16) + 0.5f * r3a;
        uint2 ou = { pk2(y0, y1), pk2(y2, y3) };
        *(uint2*)(xhat + ((size_t)t * 16 + b) * 256 + sl * 32 + colg * 4) = ou;
      }
    }
  }
}

// ---------------- K3: LayerNorm in place over x_hat rows ----------------
__global__ __launch_bounds__(256) void k_ln(
    unsigned short* xh, const float* __restrict__ g, const float* __restrict__ bta)
{
  int row = blockIdx.x * 4 + (threadIdx.x >> 6);
  int lane = threadIdx.x & 63;
  size_t base = (size_t)row * 256 + lane * 4;
  uint2 raw = *(const uint2*)(xh + base);
  float v0 = bf2f(raw.x), v1 = bf2f(raw.x >> 16), v2 = bf2f(raw.y), v3 = bf2f(raw.y >> 16);
  float s1 = v0 + v1 + v2 + v3;
  float s2 = v0 * v0 + v1 * v1 + v2 * v2 + v3 * v3;
  #pragma unroll
  for (int off = 1; off < 64; off <<= 1) { s1 += __shfl_xor(s1, off); s2 += __shfl_xor(s2, off); }
  float mu = s1 * (1.f / 256.f);
  float var = s2 * (1.f / 256.f) - mu * mu;
  float rs = rsqrtf(var + 1e-5f);
  int c = lane * 4;
  float y0 = (v0 - mu) * rs * g[c] + bta[c];
  float y1 = (v1 - mu) * rs * g[c + 1] + bta[c + 1];
  float y2 = (v2 - mu) * rs * g[c + 2] + bta[c + 2];
  float y3 = (v3 - mu) * rs * g[c + 3] + bta[c + 3];
  uint2 ou = { pk2(y0, y1), pk2(y2, y3) };
  *(uint2*)(xh + base) = ou;
}

// ---------------- K4: logits = LN(x_hat) @ Wo^T + bo -> out (B,L,V) f32 ----------------
__global__ __launch_bounds__(256) void k_logits(
    const unsigned short* __restrict__ ln, const float* __restrict__ Wo,
    const float* __restrict__ bo, float* __restrict__ out)
{
  __shared__ unsigned short As[64 * KPAD];
  __shared__ unsigned short Bs[64 * KPAD];
  const int tid = threadIdx.x, lane = tid & 63, wv = tid >> 6;
  const int m0 = blockIdx.y * 64, n0 = blockIdx.x * 64;
  const int sr = tid >> 2, skc = (tid & 3) * 8;
  const unsigned short* asrc = ln + (size_t)(m0 + sr) * 256 + skc;
  const int brow = n0 + sr;
  const bool bok = brow < V_SZ;
  const float* bsrc = Wo + (size_t)(bok ? brow : 0) * 256 + skc;

  f32x4 acc[4];
  #pragma unroll
  for (int i = 0; i < 4; ++i) acc[i] = 0.f;

  for (int ks = 0; ks < 8; ++ks) {
    __syncthreads();
    *(uint4*)&As[sr * KPAD + skc] = *(const uint4*)(asrc + ks * 32);
    uint4 ub = {0u, 0u, 0u, 0u};
    if (bok) {
      float4 q0 = *(const float4*)(bsrc + ks * 32);
      float4 q1 = *(const float4*)(bsrc + ks * 32 + 4);
      ub.x = pk2(q0.x, q0.y); ub.y = pk2(q0.z, q0.w);
      ub.z = pk2(q1.x, q1.y); ub.w = pk2(q1.z, q1.w);
    }
    *(uint4*)&Bs[sr * KPAD + skc] = ub;
    __syncthreads();
    bf16x8 af = *(const bf16x8*)&As[(wv * 16 + (lane & 15)) * KPAD + (lane >> 4) * 8];
    #pragma unroll
    for (int ns = 0; ns < 4; ++ns) {
      bf16x8 bfv = *(const bf16x8*)&Bs[(ns * 16 + (lane & 15)) * KPAD + (lane >> 4) * 8];
      acc[ns] = __builtin_amdgcn_mfma_f32_16x16x32_bf16(af, bfv, acc[ns], 0, 0, 0);
    }
  }
  const int mrow = m0 + wv * 16 + 4 * (lane >> 4);
  const int ncol = n0 + (lane & 15);
  #pragma unroll
  for (int ns = 0; ns < 4; ++ns) {
    int col = ncol + ns * 16;
    if (col < V_SZ) {
      float bv = bo[col];
      #pragma unroll
      for (int rr = 0; rr < 4; ++rr) {
        int row = mrow + rr;
        out[(size_t)(row & 15) * ((size_t)L_SEQ * V_SZ) + (size_t)(row >> 4) * V_SZ + col] =
            acc[ns][rr] + bv;
      }
    }
  }
}

extern "C" void kernel_launch(void* const* d_in, const int* in_sizes, int n_in,
                              void* d_out, int out_size, void* d_ws, size_t ws_size,
                              hipStream_t stream)
{
  const int*   tokens = (const int*)d_in[0];
  const float* emb    = (const float*)d_in[1];
  const float* Wih    = (const float*)d_in[2];
  const float* Whh    = (const float*)d_in[3];
  const float* bih    = (const float*)d_in[4];
  const float* bhh    = (const float*)d_in[5];
  const float* Wg     = (const float*)d_in[6];
  const float* bg     = (const float*)d_in[7];
  const float* Wx     = (const float*)d_in[8];
  const float* bx     = (const float*)d_in[9];
  const float* Wp     = (const float*)d_in[10];
  const float* bp     = (const float*)d_in[11];
  const float* lng    = (const float*)d_in[12];
  const float* lnb    = (const float*)d_in[13];
  const float* Wo     = (const float*)d_in[14];
  const float* bo     = (const float*)d_in[15];
  float* out = (float*)d_out;

  char* ws = (char*)d_ws;
  size_t off = 0;
  auto take = [&](size_t bytes) -> char* {
    char* p = ws + off;
    off += (bytes + 255) & ~(size_t)255;
    return p;
  };
  unsigned short* giT    = (unsigned short*)take((size_t)1024 * 1536 * 16 * 2);        // 50.33 MB
  u32x4* recS            = (u32x4*)take((size_t)REC_DEPTH * 16 * 128 * 16);            // 2.10 MB ring
  unsigned short* xhat   = (unsigned short*)take((size_t)1024 * 16 * 256 * 2);         // 8.39 MB
  unsigned long long* hq = (unsigned long long*)take((size_t)HQ_DEPTH * 4096 * 8);     // 1.05 MB ring
  if (off > ws_size) return;

  // rings carry embedded step-tags; zero them every call so no stale tag
  // (or 0xAA poison) can false-trigger.
  (void)hipMemsetAsync(recS, 0, (size_t)REC_DEPTH * 16 * 128 * 16, stream);
  (void)hipMemsetAsync(hq, 0, (size_t)HQ_DEPTH * 4096 * 8, stream);

  k_gi<<<dim3(24, 256), 256, 0, stream>>>(tokens, emb, Wih, bih, giT);
  k_scan<<<56, 256, 0, stream>>>(giT, Whh, bhh, Wg, bg, Wx, bx, Wp, bp,
                                 recS, xhat, hq);
  k_ln<<<4096, 256, 0, stream>>>(xhat, lng, lnb);
  k_logits<<<dim3(157, 256), 256, 0, stream>>>(xhat, Wo, bo, out);
}

// Round 12
// 3795.437 us; speedup vs baseline: 1.2825x; 1.2825x over previous
//
#include <hip/hip_runtime.h>

#define L_SEQ 1024
#define B_SZ  16
#define D_SZ  512
#define V_SZ  10000
#define HQ_DEPTH 32    // h ring (32 KB/slot); gh skew <=1, gxp lag << 30
#define REC_DEPTH 64   // record ring; consumer lag << 62
#define WSTR 536       // wlds row stride in u16: 268 words % 32 = 12 -> 2-way (free)
#define PW_T 272       // pscr tile stride in f32 (16 rows x 17)
#define PW_WAVE 1632   // 6 tiles x 272
#define PW_BUF 6528    // 4 waves x 1632

typedef __attribute__((ext_vector_type(8))) short bf16x8;
typedef __attribute__((ext_vector_type(4))) float f32x4;
typedef __attribute__((ext_vector_type(4))) unsigned int u32x4;
typedef __attribute__((ext_vector_type(2))) unsigned int u32x2;

__device__ __forceinline__ float bf2f(unsigned int u) {
  unsigned int x = (u & 0xffffu) << 16;
  return __builtin_bit_cast(float, x);
}
__device__ __forceinline__ unsigned short f2bf(float f) {
  unsigned int x = __builtin_bit_cast(unsigned int, f);
  x += 0x7fffu + ((x >> 16) & 1u);
  return (unsigned short)(x >> 16);
}
__device__ __forceinline__ unsigned int pk2(float lo, float hi) {
  return (unsigned int)f2bf(lo) | ((unsigned int)f2bf(hi) << 16);
}
__device__ __forceinline__ float sigm(float x) { return 1.f / (1.f + __expf(-x)); }
__device__ __forceinline__ float tanhfast(float x) {
  x = fminf(fmaxf(x, -15.f), 15.f);
  float e = __expf(2.f * x);
  return (e - 1.f) / (e + 1.f);
}

#define KPAD 40

// ---------------- K1: gi = gather(emb, tokens) @ W_ih^T + b_ih ----------------
__global__ __launch_bounds__(256) void k_gi(
    const int* __restrict__ tokens, const float* __restrict__ emb,
    const float* __restrict__ Wih, const float* __restrict__ bih,
    unsigned short* __restrict__ giT)
{
  __shared__ unsigned short As[64 * KPAD];
  __shared__ unsigned short Bs[64 * KPAD];
  const int tid = threadIdx.x, lane = tid & 63, wv = tid >> 6;
  const int m0 = blockIdx.y * 64, n0 = blockIdx.x * 64;
  const int sr = tid >> 2, skc = (tid & 3) * 8;
  const int grow = m0 + sr;
  const int tok = tokens[((grow & 15) << 10) + (grow >> 4)];
  const float* asrc = emb + (size_t)tok * 512 + skc;
  const float* bsrc = Wih + (size_t)(n0 + sr) * 512 + skc;

  f32x4 acc[4];
  #pragma unroll
  for (int i = 0; i < 4; ++i) acc[i] = 0.f;

  for (int ks = 0; ks < 16; ++ks) {
    __syncthreads();
    float4 a0 = *(const float4*)(asrc + ks * 32);
    float4 a1 = *(const float4*)(asrc + ks * 32 + 4);
    float4 q0 = *(const float4*)(bsrc + ks * 32);
    float4 q1 = *(const float4*)(bsrc + ks * 32 + 4);
    uint4 ua = { pk2(a0.x, a0.y), pk2(a0.z, a0.w), pk2(a1.x, a1.y), pk2(a1.z, a1.w) };
    uint4 ub = { pk2(q0.x, q0.y), pk2(q0.z, q0.w), pk2(q1.x, q1.y), pk2(q1.z, q1.w) };
    *(uint4*)&As[sr * KPAD + skc] = ua;
    *(uint4*)&Bs[sr * KPAD + skc] = ub;
    __syncthreads();
    bf16x8 af = *(const bf16x8*)&As[(wv * 16 + (lane & 15)) * KPAD + (lane >> 4) * 8];
    #pragma unroll
    for (int ns = 0; ns < 4; ++ns) {
      bf16x8 bfv = *(const bf16x8*)&Bs[(ns * 16 + (lane & 15)) * KPAD + (lane >> 4) * 8];
      acc[ns] = __builtin_amdgcn_mfma_f32_16x16x32_bf16(af, bfv, acc[ns], 0, 0, 0);
    }
  }
  const int mrow = m0 + wv * 16 + 4 * (lane >> 4);
  const int ncol = n0 + (lane & 15);
  #pragma unroll
  for (int ns = 0; ns < 4; ++ns) {
    int col = ncol + ns * 16;
    float bv = bih[col];
    #pragma unroll
    for (int rr = 0; rr < 4; ++rr) {
      int row = mrow + rr;
      giT[((size_t)(row >> 4) * 1536 + col) * 16 + (row & 15)] = f2bf(acc[ns][rr] + bv);
    }
  }
}

#define ISSUE_BATCH(R0,R1,R2,R3,R4,R5,R6,R7,PTR)                       \
  asm volatile(                                                        \
    "global_load_dwordx4 %0, %8, off sc0 sc1\n\t"                      \
    "global_load_dwordx4 %1, %8, off offset:16 sc0 sc1\n\t"            \
    "global_load_dwordx4 %2, %8, off offset:128 sc0 sc1\n\t"           \
    "global_load_dwordx4 %3, %8, off offset:144 sc0 sc1\n\t"           \
    "global_load_dwordx4 %4, %8, off offset:256 sc0 sc1\n\t"           \
    "global_load_dwordx4 %5, %8, off offset:272 sc0 sc1\n\t"           \
    "global_load_dwordx4 %6, %8, off offset:384 sc0 sc1\n\t"           \
    "global_load_dwordx4 %7, %8, off offset:400 sc0 sc1"               \
    : "=&v"(R0), "=&v"(R1), "=&v"(R2), "=&v"(R3),                      \
      "=&v"(R4), "=&v"(R5), "=&v"(R6), "=&v"(R7)                       \
    : "v"(PTR) : "memory")

#define TAGS_OK(R0,R1,R2,R3,R4,R5,R6,R7,TV)                            \
  ((R0.y == TV) & (R0.w == TV) & (R1.y == TV) & (R1.w == TV) &         \
   (R2.y == TV) & (R2.w == TV) & (R3.y == TV) & (R3.w == TV) &         \
   (R4.y == TV) & (R4.w == TV) & (R5.y == TV) & (R5.w == TV) &         \
   (R6.y == TV) & (R6.w == TV) & (R7.y == TV) & (R7.w == TV))

// ---------------- K2: persistent fused scan, K-split tagged exchange ----------------
// Exact R10 structure (best verified: 3.25ms). Only change: slack-tolerant
// pollers back off harder (gxp sleep 16, consumers sleep 32) to cut LLC
// contention that inflates the gh critical-path poll RT.
__global__ __launch_bounds__(256) void k_scan(
    const unsigned short* __restrict__ giT,
    const float* __restrict__ Whh, const float* __restrict__ bhh,
    const float* __restrict__ Wg, const float* __restrict__ bg,
    const float* __restrict__ Wx, const float* __restrict__ bx,
    const float* __restrict__ Wp, const float* __restrict__ bp,
    u32x4* __restrict__ recS, unsigned short* __restrict__ xhat,
    unsigned long long* __restrict__ hq)
{
  __shared__ char smem[155136];
  const int tid = threadIdx.x;
  const int lane = tid & 63, v = tid >> 6;
  const int wid = blockIdx.x;

  if (wid < 24) {
    const bool isGH = (wid < 16);
    const int w = isGH ? wid : (wid - 16);
    unsigned short* wlds = (unsigned short*)smem;   // 96 x 536 u16 = 102912 B
    float* pscr = (float*)(smem + 102912);          // 2 bufs x 4 waves x 6 x 272 f32

    for (int row = v; row < 96; row += 4) {
      const float* src;
      if (isGH) {
        src = Whh + ((size_t)(row >> 5) * 512 + w * 32 + (row & 31)) * 512;
      } else {
        int m = row >> 5;
        const float* Wm = (m == 0) ? Wg : (m == 1) ? Wx : Wp;
        src = Wm + (size_t)(w * 32 + (row & 31)) * 512;
      }
      float4 p0 = *(const float4*)(src + lane * 8);
      float4 p1 = *(const float4*)(src + lane * 8 + 4);
      uint4 uu = { pk2(p0.x, p0.y), pk2(p0.z, p0.w), pk2(p1.x, p1.y), pk2(p1.z, p1.w) };
      *(uint4*)&wlds[row * WSTR + lane * 8] = uu;
    }
    __syncthreads();

    const int b_ = lane & 15, hi = lane >> 4;
    const int bbh = tid & 15, dph = tid >> 4;   // gh pointwise mapping
    const int bbx = tid >> 4, dpx = tid & 15;   // gxp pointwise mapping

    float bhr1 = 0, bhz1 = 0, bhn1 = 0, bhr2 = 0, bhz2 = 0, bhn2 = 0;
    float bgc0 = 0, bgc1 = 0, bxc0 = 0, bxc1 = 0, bpc0 = 0, bpc1 = 0;
    float hprev1 = 0.f, hprev2 = 0.f;
    if (isGH) {
      int d0 = w * 32 + 2 * dph, d1 = d0 + 1;
      bhr1 = bhh[d0]; bhz1 = bhh[512 + d0]; bhn1 = bhh[1024 + d0];
      bhr2 = bhh[d1]; bhz2 = bhh[512 + d1]; bhn2 = bhh[1024 + d1];
    } else {
      int d0 = w * 32 + 2 * dpx, d1 = d0 + 1;
      bgc0 = bg[d0]; bgc1 = bg[d1];
      bxc0 = bx[d0]; bxc1 = bx[d1];
      bpc0 = bp[d0]; bpc1 = bp[d1];
    }

    float gir1 = 0, giz1 = 0, gin1 = 0, gir2 = 0, giz2 = 0, gin2 = 0;
    if (isGH) {
      int d0 = w * 32 + 2 * dph, d1 = d0 + 1;
      const unsigned short* gib = giT + bbh;
      gir1 = bf2f(gib[(size_t)d0 * 16]);
      giz1 = bf2f(gib[(size_t)(512 + d0) * 16]);
      gin1 = bf2f(gib[(size_t)(1024 + d0) * 16]);
      gir2 = bf2f(gib[(size_t)d1 * 16]);
      giz2 = bf2f(gib[(size_t)(512 + d1) * 16]);
      gin2 = bf2f(gib[(size_t)(1024 + d1) * 16]);
    }

    // B-fragment base for this wave's K-quarter (kk = 4v..4v+3)
    const unsigned short* bqbase = wlds + (size_t)b_ * WSTR + (size_t)(4 * v) * 32 + hi * 8;
    const size_t pofs = (size_t)b_ * 256 + 64 * v + 4 * hi;

    #pragma unroll 1
    for (int t = 0; t < L_SEQ; ++t) {
      const int pt = isGH ? (t - 1) : t;   // h step consumed this iteration
      f32x4 pacc[6];
      #pragma unroll
      for (int i = 0; i < 6; ++i) pacc[i] = 0.f;

      if (pt >= 0) {
        const unsigned long long* hsrc = hq + (size_t)(pt & (HQ_DEPTH - 1)) * 4096 + pofs;
        const unsigned int tv = (unsigned int)(pt + 1);
        u32x4 q0, q1, q2, q3, q4, q5, q6, q7;
        int spins = 0;
        for (;;) {
          ISSUE_BATCH(q0, q1, q2, q3, q4, q5, q6, q7, hsrc);
          asm volatile("s_waitcnt vmcnt(0)" ::: "memory");
          if (__all(TAGS_OK(q0, q1, q2, q3, q4, q5, q6, q7, tv))) break;
          if (!isGH) __builtin_amdgcn_s_sleep(16);  // gxp: a full step of slack
          if (++spins > 2000000) break;
        }
        u32x4 f0 = { q0.x, q0.z, q1.x, q1.z };
        u32x4 f1 = { q2.x, q2.z, q3.x, q3.z };
        u32x4 f2 = { q4.x, q4.z, q5.x, q5.z };
        u32x4 f3 = { q6.x, q6.z, q7.x, q7.z };
        bf16x8 a0 = __builtin_bit_cast(bf16x8, f0);
        bf16x8 a1 = __builtin_bit_cast(bf16x8, f1);
        bf16x8 a2 = __builtin_bit_cast(bf16x8, f2);
        bf16x8 a3 = __builtin_bit_cast(bf16x8, f3);
        #pragma unroll
        for (int T = 0; T < 6; ++T) {
          const unsigned short* bp0 = bqbase + (size_t)T * (16 * WSTR);
          bf16x8 w0 = *(const bf16x8*)(bp0);
          bf16x8 w1 = *(const bf16x8*)(bp0 + 32);
          bf16x8 w2 = *(const bf16x8*)(bp0 + 64);
          bf16x8 w3 = *(const bf16x8*)(bp0 + 96);
          pacc[T] = __builtin_amdgcn_mfma_f32_16x16x32_bf16(a0, w0, pacc[T], 0, 0, 0);
          pacc[T] = __builtin_amdgcn_mfma_f32_16x16x32_bf16(a1, w1, pacc[T], 0, 0, 0);
          pacc[T] = __builtin_amdgcn_mfma_f32_16x16x32_bf16(a2, w2, pacc[T], 0, 0, 0);
          pacc[T] = __builtin_amdgcn_mfma_f32_16x16x32_bf16(a3, w3, pacc[T], 0, 0, 0);
        }
      }

      {
        float* pw = pscr + (size_t)(t & 1) * PW_BUF + (size_t)v * PW_WAVE;
        #pragma unroll
        for (int T = 0; T < 6; ++T) {
          #pragma unroll
          for (int rr = 0; rr < 4; ++rr)
            pw[T * PW_T + (4 * hi + rr) * 17 + b_] = pacc[T][rr];
        }
      }
      __syncthreads();   // single per-step barrier; nothing fresh in flight here

      const float* pb = pscr + (size_t)(t & 1) * PW_BUF;
      if (isGH) {
        const int Tr = dph >> 3, j0 = (2 * dph) & 15;
        const int base0 = Tr * PW_T + bbh * 17 + j0;
        float ar1 = pb[base0]              + pb[PW_WAVE + base0]              + pb[2*PW_WAVE + base0]              + pb[3*PW_WAVE + base0];
        float ar2 = pb[base0 + 1]          + pb[PW_WAVE + base0 + 1]          + pb[2*PW_WAVE + base0 + 1]          + pb[3*PW_WAVE + base0 + 1];
        float az1 = pb[base0 + 2*PW_T]     + pb[PW_WAVE + base0 + 2*PW_T]     + pb[2*PW_WAVE + base0 + 2*PW_T]     + pb[3*PW_WAVE + base0 + 2*PW_T];
        float az2 = pb[base0 + 2*PW_T + 1] + pb[PW_WAVE + base0 + 2*PW_T + 1] + pb[2*PW_WAVE + base0 + 2*PW_T + 1] + pb[3*PW_WAVE + base0 + 2*PW_T + 1];
        float an1 = pb[base0 + 4*PW_T]     + pb[PW_WAVE + base0 + 4*PW_T]     + pb[2*PW_WAVE + base0 + 4*PW_T]     + pb[3*PW_WAVE + base0 + 4*PW_T];
        float an2 = pb[base0 + 4*PW_T + 1] + pb[PW_WAVE + base0 + 4*PW_T + 1] + pb[2*PW_WAVE + base0 + 4*PW_T + 1] + pb[3*PW_WAVE + base0 + 4*PW_T + 1];
        float r1 = sigm(ar1 + gir1 + bhr1);
        float z1 = sigm(az1 + giz1 + bhz1);
        float n1 = tanhfast(gin1 + r1 * (an1 + bhn1));
        float h1 = (1.f - z1) * n1 + z1 * hprev1; hprev1 = h1;
        float r2 = sigm(ar2 + gir2 + bhr2);
        float z2 = sigm(az2 + giz2 + bhz2);
        float n2 = tanhfast(gin2 + r2 * (an2 + bhn2));
        float h2 = (1.f - z2) * n2 + z2 * hprev2; hprev2 = h2;
        // h publish: fire-and-forget atomic (performed AT the LLC)
        u32x2 hv = { pk2(h1, h2), (unsigned int)(t + 1) };
        unsigned long long* hdst = hq + (size_t)(t & (HQ_DEPTH - 1)) * 4096
                                      + (size_t)bbh * 256 + w * 16 + dph;
        asm volatile("global_atomic_swap_x2 %0, %1, off sc1"
                     :: "v"(hdst), "v"(hv) : "memory");
        // gi(t+1) prefetch at tail: lands during the next poll
        if (t + 1 < L_SEQ) {
          int d0 = w * 32 + 2 * dph, d1 = d0 + 1;
          const unsigned short* gib = giT + (size_t)(t + 1) * 1536 * 16 + bbh;
          gir1 = bf2f(gib[(size_t)d0 * 16]);
          giz1 = bf2f(gib[(size_t)(512 + d0) * 16]);
          gin1 = bf2f(gib[(size_t)(1024 + d0) * 16]);
          gir2 = bf2f(gib[(size_t)d1 * 16]);
          giz2 = bf2f(gib[(size_t)(512 + d1) * 16]);
          gin2 = bf2f(gib[(size_t)(1024 + d1) * 16]);
        }
      } else {
        const int Tg = dpx >> 3, j0 = (2 * dpx) & 15;
        const int base0 = Tg * PW_T + bbx * 17 + j0;
        float g0 = pb[base0]              + pb[PW_WAVE + base0]              + pb[2*PW_WAVE + base0]              + pb[3*PW_WAVE + base0];
        float g1 = pb[base0 + 1]          + pb[PW_WAVE + base0 + 1]          + pb[2*PW_WAVE + base0 + 1]          + pb[3*PW_WAVE + base0 + 1];
        float x0 = pb[base0 + 2*PW_T]     + pb[PW_WAVE + base0 + 2*PW_T]     + pb[2*PW_WAVE + base0 + 2*PW_T]     + pb[3*PW_WAVE + base0 + 2*PW_T];
        float x1 = pb[base0 + 2*PW_T + 1] + pb[PW_WAVE + base0 + 2*PW_T + 1] + pb[2*PW_WAVE + base0 + 2*PW_T + 1] + pb[3*PW_WAVE + base0 + 2*PW_T + 1];
        float p0 = pb[base0 + 4*PW_T]     + pb[PW_WAVE + base0 + 4*PW_T]     + pb[2*PW_WAVE + base0 + 4*PW_T]     + pb[3*PW_WAVE + base0 + 4*PW_T];
        float p1 = pb[base0 + 4*PW_T + 1] + pb[PW_WAVE + base0 + 4*PW_T + 1] + pb[2*PW_WAVE + base0 + 4*PW_T + 1] + pb[3*PW_WAVE + base0 + 4*PW_T + 1];
        g0 += bgc0; g1 += bgc1; x0 += bxc0; x1 += bxc1; p0 += bpc0; p1 += bpc1;
        u32x4 rec = { pk2(g0, g1), pk2(x0, x1), pk2(p0, p1), (unsigned int)(t + 1) };
        u32x4* rdst = recS + ((size_t)(t & (REC_DEPTH - 1)) * 16 + bbx) * 128 + w * 16 + dpx;
        asm volatile("global_store_dwordx4 %0, %1, off sc0 sc1" :: "v"(rdst), "v"(rec) : "memory");
      }
    }
  } else {
    // ---- consumers: 32 blocks x 4 independent waves = 128 M-slices ----
    const int id = wid - 24;            // 0..31
    const int b = id >> 1, sg = id & 1;
    const int sl = sg * 4 + v;          // slice 0..7 (32 cols each)
    float* Msh = (float*)(smem + v * 32768);  // [256][32] f32
    const int colg = lane & 7, dgs = lane >> 3;
    for (int i = lane * 4; i < 8192; i += 256) *(float4*)&Msh[i] = float4{0.f, 0.f, 0.f, 0.f};
    #pragma unroll 1
    for (int t = 0; t < L_SEQ; ++t) {
      const u32x4* rp = recS + ((size_t)(t & (REC_DEPTH - 1)) * 16 + b) * 128 + 2 * lane;
      const unsigned int tagv = (unsigned int)(t + 1);
      u32x4 r0, r1;
      int spins = 0;
      for (;;) {
        asm volatile(
          "global_load_dwordx4 %0, %2, off sc0 sc1\n\t"
          "global_load_dwordx4 %1, %2, off offset:16 sc0 sc1\n\t"
          "s_waitcnt vmcnt(0)"
          : "=&v"(r0), "=&v"(r1) : "v"(rp) : "memory");
        if (__all((r0.w == tagv) && (r1.w == tagv))) break;
        __builtin_amdgcn_s_sleep(32);  // huge slack (REC ring = 64 steps)
        if (++spins > 2000000) break;
      }
      const int lx = sl * 8 + colg;
      unsigned int xa = (unsigned int)__shfl((int)r0.y, lx);
      unsigned int xb = (unsigned int)__shfl((int)r1.y, lx);
      unsigned int pa = (unsigned int)__shfl((int)r0.z, lx);
      unsigned int pb2 = (unsigned int)__shfl((int)r1.z, lx);
      float xv0 = bf2f(xa), xv1 = bf2f(xa >> 16), xv2 = bf2f(xb), xv3 = bf2f(xb >> 16);
      float r0a = 0, r1a = 0, r2a = 0, r3a = 0;
      #pragma unroll
      for (int ic = 0; ic < 8; ++ic) {
        const int ls = dgs * 8 + ic;
        unsigned int ga = (unsigned int)__shfl((int)r0.x, ls);
        unsigned int gb = (unsigned int)__shfl((int)r1.x, ls);
        float gj[4] = { bf2f(ga), bf2f(ga >> 16), bf2f(gb), bf2f(gb >> 16) };
        int dg = dgs * 32 + ic * 4;
        #pragma unroll
        for (int j = 0; j < 4; ++j) {
          float4* mp = (float4*)&Msh[(dg + j) * 32 + colg * 4];
          float4 m = *mp;
          r0a += gj[j] * m.x; r1a += gj[j] * m.y; r2a += gj[j] * m.z; r3a += gj[j] * m.w;
          m.x += gj[j] * xv0; m.y += gj[j] * xv1; m.z += gj[j] * xv2; m.w += gj[j] * xv3;
          *mp = m;
        }
      }
      #pragma unroll
      for (int off = 8; off < 64; off <<= 1) {
        r0a += __shfl_xor(r0a, off); r1a += __shfl_xor(r1a, off);
        r2a += __shfl_xor(r2a, off); r3a += __shfl_xor(r3a, off);
      }
      if (dgs == 0) {
        float y0 = 0.5f * bf2f(pa) + 0.5f * r0a;
        float y1 = 0.5f * bf2f(pa >> 16) + 0.5f * r1a;
        float y2 = 0.5f * bf2f(pb2) + 0.5f * r2a;
        float y3 = 0.5f * bf2f(pb2 >> 16) + 0.5f * r3a;
        uint2 ou = { pk2(y0, y1), pk2(y2, y3) };
        *(uint2*)(xhat + ((size_t)t * 16 + b) * 256 + sl * 32 + colg * 4) = ou;
      }
    }
  }
}

// ---------------- K3: LayerNorm in place over x_hat rows ----------------
__global__ __launch_bounds__(256) void k_ln(
    unsigned short* xh, const float* __restrict__ g, const float* __restrict__ bta)
{
  int row = blockIdx.x * 4 + (threadIdx.x >> 6);
  int lane = threadIdx.x & 63;
  size_t base = (size_t)row * 256 + lane * 4;
  uint2 raw = *(const uint2*)(xh + base);
  float v0 = bf2f(raw.x), v1 = bf2f(raw.x >> 16), v2 = bf2f(raw.y), v3 = bf2f(raw.y >> 16);
  float s1 = v0 + v1 + v2 + v3;
  float s2 = v0 * v0 + v1 * v1 + v2 * v2 + v3 * v3;
  #pragma unroll
  for (int off = 1; off < 64; off <<= 1) { s1 += __shfl_xor(s1, off); s2 += __shfl_xor(s2, off); }
  float mu = s1 * (1.f / 256.f);
  float var = s2 * (1.f / 256.f) - mu * mu;
  float rs = rsqrtf(var + 1e-5f);
  int c = lane * 4;
  float y0 = (v0 - mu) * rs * g[c] + bta[c];
  float y1 = (v1 - mu) * rs * g[c + 1] + bta[c + 1];
  float y2 = (v2 - mu) * rs * g[c + 2] + bta[c + 2];
  float y3 = (v3 - mu) * rs * g[c + 3] + bta[c + 3];
  uint2 ou = { pk2(y0, y1), pk2(y2, y3) };
  *(uint2*)(xh + base) = ou;
}

// ---------------- K4: logits = LN(x_hat) @ Wo^T + bo -> out (B,L,V) f32 ----------------
// New epilogue: per-wave LDS transpose -> 64B-contiguous dwordx4 stores.
__global__ __launch_bounds__(256) void k_logits(
    const unsigned short* __restrict__ ln, const float* __restrict__ Wo,
    const float* __restrict__ bo, float* __restrict__ out)
{
  __shared__ unsigned short As[64 * KPAD];
  __shared__ unsigned short Bs[64 * KPAD];
  __shared__ float Ts[4][16 * 68];   // per-wave 16x64 tile, stride 68
  const int tid = threadIdx.x, lane = tid & 63, wv = tid >> 6;
  const int m0 = blockIdx.y * 64, n0 = blockIdx.x * 64;
  const int sr = tid >> 2, skc = (tid & 3) * 8;
  const unsigned short* asrc = ln + (size_t)(m0 + sr) * 256 + skc;
  const int brow = n0 + sr;
  const bool bok = brow < V_SZ;
  const float* bsrc = Wo + (size_t)(bok ? brow : 0) * 256 + skc;

  f32x4 acc[4];
  #pragma unroll
  for (int i = 0; i < 4; ++i) acc[i] = 0.f;

  for (int ks = 0; ks < 8; ++ks) {
    __syncthreads();
    *(uint4*)&As[sr * KPAD + skc] = *(const uint4*)(asrc + ks * 32);
    uint4 ub = {0u, 0u, 0u, 0u};
    if (bok) {
      float4 q0 = *(const float4*)(bsrc + ks * 32);
      float4 q1 = *(const float4*)(bsrc + ks * 32 + 4);
      ub.x = pk2(q0.x, q0.y); ub.y = pk2(q0.z, q0.w);
      ub.z = pk2(q1.x, q1.y); ub.w = pk2(q1.z, q1.w);
    }
    *(uint4*)&Bs[sr * KPAD + skc] = ub;
    __syncthreads();
    bf16x8 af = *(const bf16x8*)&As[(wv * 16 + (lane & 15)) * KPAD + (lane >> 4) * 8];
    #pragma unroll
    for (int ns = 0; ns < 4; ++ns) {
      bf16x8 bfv = *(const bf16x8*)&Bs[(ns * 16 + (lane & 15)) * KPAD + (lane >> 4) * 8];
      acc[ns] = __builtin_amdgcn_mfma_f32_16x16x32_bf16(af, bfv, acc[ns], 0, 0, 0);
    }
  }
  // stage C tile (bias folded) into this wave's private LDS tile
  {
    const int rbase = 4 * (lane >> 4);      // local row group
    const int cl = lane & 15;
    #pragma unroll
    for (int ns = 0; ns < 4; ++ns) {
      int col = n0 + cl + ns * 16;
      float bv = (col < V_SZ) ? bo[col] : 0.f;
      #pragma unroll
      for (int rr = 0; rr < 4; ++rr)
        Ts[wv][(rbase + rr) * 68 + cl + ns * 16] = acc[ns][rr] + bv;
    }
  }
  // intra-wave only: ds_write -> ds_read ordering handled by lgkmcnt
  {
    const int rloc = lane >> 2;             // 0..15
    const int c0 = (lane & 3) * 16;         // 0,16,32,48
    const int grow = m0 + wv * 16 + rloc;   // global M row
    if (n0 + c0 + 16 <= V_SZ) {             // V is 16-aligned -> full-chunk guard
      float* dst = out + (size_t)(grow & 15) * ((size_t)L_SEQ * V_SZ)
                       + (size_t)(grow >> 4) * V_SZ + n0 + c0;
      const float* srcT = &Ts[wv][rloc * 68 + c0];
      #pragma unroll
      for (int q = 0; q < 4; ++q)
        *(float4*)(dst + 4 * q) = *(const float4*)(srcT + 4 * q);
    }
  }
}

extern "C" void kernel_launch(void* const* d_in, const int* in_sizes, int n_in,
                              void* d_out, int out_size, void* d_ws, size_t ws_size,
                              hipStream_t stream)
{
  const int*   tokens = (const int*)d_in[0];
  const float* emb    = (const float*)d_in[1];
  const float* Wih    = (const float*)d_in[2];
  const float* Whh    = (const float*)d_in[3];
  const float* bih    = (const float*)d_in[4];
  const float* bhh    = (const float*)d_in[5];
  const float* Wg     = (const float*)d_in[6];
  const float* bg     = (const float*)d_in[7];
  const float* Wx     = (const float*)d_in[8];
  const float* bx     = (const float*)d_in[9];
  const float* Wp     = (const float*)d_in[10];
  const float* bp     = (const float*)d_in[11];
  const float* lng    = (const float*)d_in[12];
  const float* lnb    = (const float*)d_in[13];
  const float* Wo     = (const float*)d_in[14];
  const float* bo     = (const float*)d_in[15];
  float* out = (float*)d_out;

  char* ws = (char*)d_ws;
  size_t off = 0;
  auto take = [&](size_t bytes) -> char* {
    char* p = ws + off;
    off += (bytes + 255) & ~(size_t)255;
    return p;
  };
  unsigned short* giT    = (unsigned short*)take((size_t)1024 * 1536 * 16 * 2);        // 50.33 MB
  u32x4* recS            = (u32x4*)take((size_t)REC_DEPTH * 16 * 128 * 16);            // 2.10 MB ring
  unsigned short* xhat   = (unsigned short*)take((size_t)1024 * 16 * 256 * 2);         // 8.39 MB
  unsigned long long* hq = (unsigned long long*)take((size_t)HQ_DEPTH * 4096 * 8);     // 1.05 MB ring
  if (off > ws_size) return;

  // rings carry embedded step-tags; zero them every call so no stale tag
  // (or 0xAA poison) can false-trigger.
  (void)hipMemsetAsync(recS, 0, (size_t)REC_DEPTH * 16 * 128 * 16, stream);
  (void)hipMemsetAsync(hq, 0, (size_t)HQ_DEPTH * 4096 * 8, stream);

  k_gi<<<dim3(24, 256), 256, 0, stream>>>(tokens, emb, Wih, bih, giT);
  k_scan<<<56, 256, 0, stream>>>(giT, Whh, bhh, Wg, bg, Wx, bx, Wp, bp,
                                 recS, xhat, hq);
  k_ln<<<4096, 256, 0, stream>>>(xhat, lng, lnb);
  k_logits<<<dim3(157, 256), 256, 0, stream>>>(xhat, Wo, bo, out);
}

// Round 13
// 3504.552 us; speedup vs baseline: 1.3890x; 1.0830x over previous
//
#include <hip/hip_runtime.h>

#define L_SEQ 1024
#define B_SZ  16
#define D_SZ  512
#define V_SZ  10000
#define HQ_DEPTH 32    // h ring (32 KB/slot); gh skew <=1, gxp lag << 30
#define REC_DEPTH 64   // record ring; consumer lag << 62
#define PW_T 272       // pscr tile stride in f32 (16 rows x 17)
#define PW_WAVE 1632   // 6 tiles x 272
#define PW_BUF 6528    // 4 waves x 1632

typedef __attribute__((ext_vector_type(8))) short bf16x8;
typedef __attribute__((ext_vector_type(4))) float f32x4;
typedef __attribute__((ext_vector_type(4))) unsigned int u32x4;
typedef __attribute__((ext_vector_type(2))) unsigned int u32x2;

__device__ __forceinline__ float bf2f(unsigned int u) {
  unsigned int x = (u & 0xffffu) << 16;
  return __builtin_bit_cast(float, x);
}
__device__ __forceinline__ unsigned short f2bf(float f) {
  unsigned int x = __builtin_bit_cast(unsigned int, f);
  x += 0x7fffu + ((x >> 16) & 1u);
  return (unsigned short)(x >> 16);
}
__device__ __forceinline__ unsigned int pk2(float lo, float hi) {
  return (unsigned int)f2bf(lo) | ((unsigned int)f2bf(hi) << 16);
}
__device__ __forceinline__ float sigm(float x) { return 1.f / (1.f + __expf(-x)); }
__device__ __forceinline__ float tanhfast(float x) {
  x = fminf(fmaxf(x, -15.f), 15.f);
  float e = __expf(2.f * x);
  return (e - 1.f) / (e + 1.f);
}

#define KPAD 40

// ---------------- K1: gi = gather(emb, tokens) @ W_ih^T + b_ih ----------------
__global__ __launch_bounds__(256) void k_gi(
    const int* __restrict__ tokens, const float* __restrict__ emb,
    const float* __restrict__ Wih, const float* __restrict__ bih,
    unsigned short* __restrict__ giT)
{
  __shared__ unsigned short As[64 * KPAD];
  __shared__ unsigned short Bs[64 * KPAD];
  const int tid = threadIdx.x, lane = tid & 63, wv = tid >> 6;
  const int m0 = blockIdx.y * 64, n0 = blockIdx.x * 64;
  const int sr = tid >> 2, skc = (tid & 3) * 8;
  const int grow = m0 + sr;
  const int tok = tokens[((grow & 15) << 10) + (grow >> 4)];
  const float* asrc = emb + (size_t)tok * 512 + skc;
  const float* bsrc = Wih + (size_t)(n0 + sr) * 512 + skc;

  f32x4 acc[4];
  #pragma unroll
  for (int i = 0; i < 4; ++i) acc[i] = 0.f;

  for (int ks = 0; ks < 16; ++ks) {
    __syncthreads();
    float4 a0 = *(const float4*)(asrc + ks * 32);
    float4 a1 = *(const float4*)(asrc + ks * 32 + 4);
    float4 q0 = *(const float4*)(bsrc + ks * 32);
    float4 q1 = *(const float4*)(bsrc + ks * 32 + 4);
    uint4 ua = { pk2(a0.x, a0.y), pk2(a0.z, a0.w), pk2(a1.x, a1.y), pk2(a1.z, a1.w) };
    uint4 ub = { pk2(q0.x, q0.y), pk2(q0.z, q0.w), pk2(q1.x, q1.y), pk2(q1.z, q1.w) };
    *(uint4*)&As[sr * KPAD + skc] = ua;
    *(uint4*)&Bs[sr * KPAD + skc] = ub;
    __syncthreads();
    bf16x8 af = *(const bf16x8*)&As[(wv * 16 + (lane & 15)) * KPAD + (lane >> 4) * 8];
    #pragma unroll
    for (int ns = 0; ns < 4; ++ns) {
      bf16x8 bfv = *(const bf16x8*)&Bs[(ns * 16 + (lane & 15)) * KPAD + (lane >> 4) * 8];
      acc[ns] = __builtin_amdgcn_mfma_f32_16x16x32_bf16(af, bfv, acc[ns], 0, 0, 0);
    }
  }
  const int mrow = m0 + wv * 16 + 4 * (lane >> 4);
  const int ncol = n0 + (lane & 15);
  #pragma unroll
  for (int ns = 0; ns < 4; ++ns) {
    int col = ncol + ns * 16;
    float bv = bih[col];
    #pragma unroll
    for (int rr = 0; rr < 4; ++rr) {
      int row = mrow + rr;
      giT[((size_t)(row >> 4) * 1536 + col) * 16 + (row & 15)] = f2bf(acc[ns][rr] + bv);
    }
  }
}

#define ISSUE_BATCH(R0,R1,R2,R3,R4,R5,R6,R7,PTR)                       \
  asm volatile(                                                        \
    "global_load_dwordx4 %0, %8, off sc0 sc1\n\t"                      \
    "global_load_dwordx4 %1, %8, off offset:16 sc0 sc1\n\t"            \
    "global_load_dwordx4 %2, %8, off offset:128 sc0 sc1\n\t"           \
    "global_load_dwordx4 %3, %8, off offset:144 sc0 sc1\n\t"           \
    "global_load_dwordx4 %4, %8, off offset:256 sc0 sc1\n\t"           \
    "global_load_dwordx4 %5, %8, off offset:272 sc0 sc1\n\t"           \
    "global_load_dwordx4 %6, %8, off offset:384 sc0 sc1\n\t"           \
    "global_load_dwordx4 %7, %8, off offset:400 sc0 sc1"               \
    : "=&v"(R0), "=&v"(R1), "=&v"(R2), "=&v"(R3),                      \
      "=&v"(R4), "=&v"(R5), "=&v"(R6), "=&v"(R7)                       \
    : "v"(PTR) : "memory")

#define TAGS_OK(R0,R1,R2,R3,R4,R5,R6,R7,TV)                            \
  ((R0.y == TV) & (R0.w == TV) & (R1.y == TV) & (R1.w == TV) &         \
   (R2.y == TV) & (R2.w == TV) & (R3.y == TV) & (R3.w == TV) &         \
   (R4.y == TV) & (R4.w == TV) & (R5.y == TV) & (R5.w == TV) &         \
   (R6.y == TV) & (R6.w == TV) & (R7.y == TV) & (R7.w == TV))

// ---------------- K2: persistent fused scan, K-split tagged exchange ----------------
// R10/R12 structure. New: producer weight fragments live in REGISTERS (24 x
// bf16x8 per wave = its K-quarter of all 6 tiles), loaded once from global at
// init. Deletes all per-step weight ds_reads + their bank conflicts + wlds.
__global__ __launch_bounds__(256) void k_scan(
    const unsigned short* __restrict__ giT,
    const float* __restrict__ Whh, const float* __restrict__ bhh,
    const float* __restrict__ Wg, const float* __restrict__ bg,
    const float* __restrict__ Wx, const float* __restrict__ bx,
    const float* __restrict__ Wp, const float* __restrict__ bp,
    u32x4* __restrict__ recS, unsigned short* __restrict__ xhat,
    unsigned long long* __restrict__ hq)
{
  __shared__ char smem[131072];
  const int tid = threadIdx.x;
  const int lane = tid & 63, v = tid >> 6;
  const int wid = blockIdx.x;

  if (wid < 24) {
    const bool isGH = (wid < 16);
    const int w = isGH ? wid : (wid - 16);
    float* pscr = (float*)smem;          // 2 bufs x 4 waves x 6 x 272 f32 = 52224 B

    const int b_ = lane & 15, hi = lane >> 4;
    const int bbh = tid & 15, dph = tid >> 4;   // gh pointwise mapping
    const int bbx = tid >> 4, dpx = tid & 15;   // gxp pointwise mapping

    // ---- register-resident weight fragments: wave v's K-quarter of 6 tiles ----
    // fragment (T,kkl): row = gate(T>>1), dim = w*32 + (T&1)*16 + b_,
    //                   K-offset = (4v+kkl)*32 + hi*8  (8 consecutive K elems)
    bf16x8 wreg[6][4];
    #pragma unroll
    for (int T = 0; T < 6; ++T) {
      const int gate = T >> 1;
      const int drow = w * 32 + (T & 1) * 16 + b_;
      const float* src;
      if (isGH) src = Whh + ((size_t)gate * 512 + drow) * 512;
      else      src = ((gate == 0) ? Wg : (gate == 1) ? Wx : Wp) + (size_t)drow * 512;
      const float* p = src + (size_t)(4 * v) * 32 + hi * 8;
      #pragma unroll
      for (int kkl = 0; kkl < 4; ++kkl) {
        float4 p0 = *(const float4*)(p + kkl * 32);
        float4 p1 = *(const float4*)(p + kkl * 32 + 4);
        u32x4 u = { pk2(p0.x, p0.y), pk2(p0.z, p0.w), pk2(p1.x, p1.y), pk2(p1.z, p1.w) };
        wreg[T][kkl] = __builtin_bit_cast(bf16x8, u);
      }
    }

    float bhr1 = 0, bhz1 = 0, bhn1 = 0, bhr2 = 0, bhz2 = 0, bhn2 = 0;
    float bgc0 = 0, bgc1 = 0, bxc0 = 0, bxc1 = 0, bpc0 = 0, bpc1 = 0;
    float hprev1 = 0.f, hprev2 = 0.f;
    if (isGH) {
      int d0 = w * 32 + 2 * dph, d1 = d0 + 1;
      bhr1 = bhh[d0]; bhz1 = bhh[512 + d0]; bhn1 = bhh[1024 + d0];
      bhr2 = bhh[d1]; bhz2 = bhh[512 + d1]; bhn2 = bhh[1024 + d1];
    } else {
      int d0 = w * 32 + 2 * dpx, d1 = d0 + 1;
      bgc0 = bg[d0]; bgc1 = bg[d1];
      bxc0 = bx[d0]; bxc1 = bx[d1];
      bpc0 = bp[d0]; bpc1 = bp[d1];
    }

    float gir1 = 0, giz1 = 0, gin1 = 0, gir2 = 0, giz2 = 0, gin2 = 0;
    if (isGH) {
      int d0 = w * 32 + 2 * dph, d1 = d0 + 1;
      const unsigned short* gib = giT + bbh;
      gir1 = bf2f(gib[(size_t)d0 * 16]);
      giz1 = bf2f(gib[(size_t)(512 + d0) * 16]);
      gin1 = bf2f(gib[(size_t)(1024 + d0) * 16]);
      gir2 = bf2f(gib[(size_t)d1 * 16]);
      giz2 = bf2f(gib[(size_t)(512 + d1) * 16]);
      gin2 = bf2f(gib[(size_t)(1024 + d1) * 16]);
    }

    const size_t pofs = (size_t)b_ * 256 + 64 * v + 4 * hi;

    #pragma unroll 1
    for (int t = 0; t < L_SEQ; ++t) {
      const int pt = isGH ? (t - 1) : t;   // h step consumed this iteration
      f32x4 pacc[6];
      #pragma unroll
      for (int i = 0; i < 6; ++i) pacc[i] = 0.f;

      if (pt >= 0) {
        const unsigned long long* hsrc = hq + (size_t)(pt & (HQ_DEPTH - 1)) * 4096 + pofs;
        const unsigned int tv = (unsigned int)(pt + 1);
        u32x4 q0, q1, q2, q3, q4, q5, q6, q7;
        int spins = 0;
        for (;;) {
          ISSUE_BATCH(q0, q1, q2, q3, q4, q5, q6, q7, hsrc);
          asm volatile("s_waitcnt vmcnt(0)" ::: "memory");
          if (__all(TAGS_OK(q0, q1, q2, q3, q4, q5, q6, q7, tv))) break;
          if (!isGH) __builtin_amdgcn_s_sleep(16);  // gxp: a full step of slack
          if (++spins > 2000000) break;
        }
        u32x4 f0 = { q0.x, q0.z, q1.x, q1.z };
        u32x4 f1 = { q2.x, q2.z, q3.x, q3.z };
        u32x4 f2 = { q4.x, q4.z, q5.x, q5.z };
        u32x4 f3 = { q6.x, q6.z, q7.x, q7.z };
        bf16x8 a0 = __builtin_bit_cast(bf16x8, f0);
        bf16x8 a1 = __builtin_bit_cast(bf16x8, f1);
        bf16x8 a2 = __builtin_bit_cast(bf16x8, f2);
        bf16x8 a3 = __builtin_bit_cast(bf16x8, f3);
        #pragma unroll
        for (int T = 0; T < 6; ++T) {
          pacc[T] = __builtin_amdgcn_mfma_f32_16x16x32_bf16(a0, wreg[T][0], pacc[T], 0, 0, 0);
          pacc[T] = __builtin_amdgcn_mfma_f32_16x16x32_bf16(a1, wreg[T][1], pacc[T], 0, 0, 0);
          pacc[T] = __builtin_amdgcn_mfma_f32_16x16x32_bf16(a2, wreg[T][2], pacc[T], 0, 0, 0);
          pacc[T] = __builtin_amdgcn_mfma_f32_16x16x32_bf16(a3, wreg[T][3], pacc[T], 0, 0, 0);
        }
      }

      {
        float* pw = pscr + (size_t)(t & 1) * PW_BUF + (size_t)v * PW_WAVE;
        #pragma unroll
        for (int T = 0; T < 6; ++T) {
          #pragma unroll
          for (int rr = 0; rr < 4; ++rr)
            pw[T * PW_T + (4 * hi + rr) * 17 + b_] = pacc[T][rr];
        }
      }
      __syncthreads();   // single per-step barrier; nothing fresh in flight here

      const float* pb = pscr + (size_t)(t & 1) * PW_BUF;
      if (isGH) {
        const int Tr = dph >> 3, j0 = (2 * dph) & 15;
        const int base0 = Tr * PW_T + bbh * 17 + j0;
        float ar1 = pb[base0]              + pb[PW_WAVE + base0]              + pb[2*PW_WAVE + base0]              + pb[3*PW_WAVE + base0];
        float ar2 = pb[base0 + 1]          + pb[PW_WAVE + base0 + 1]          + pb[2*PW_WAVE + base0 + 1]          + pb[3*PW_WAVE + base0 + 1];
        float az1 = pb[base0 + 2*PW_T]     + pb[PW_WAVE + base0 + 2*PW_T]     + pb[2*PW_WAVE + base0 + 2*PW_T]     + pb[3*PW_WAVE + base0 + 2*PW_T];
        float az2 = pb[base0 + 2*PW_T + 1] + pb[PW_WAVE + base0 + 2*PW_T + 1] + pb[2*PW_WAVE + base0 + 2*PW_T + 1] + pb[3*PW_WAVE + base0 + 2*PW_T + 1];
        float an1 = pb[base0 + 4*PW_T]     + pb[PW_WAVE + base0 + 4*PW_T]     + pb[2*PW_WAVE + base0 + 4*PW_T]     + pb[3*PW_WAVE + base0 + 4*PW_T];
        float an2 = pb[base0 + 4*PW_T + 1] + pb[PW_WAVE + base0 + 4*PW_T + 1] + pb[2*PW_WAVE + base0 + 4*PW_T + 1] + pb[3*PW_WAVE + base0 + 4*PW_T + 1];
        float r1 = sigm(ar1 + gir1 + bhr1);
        float z1 = sigm(az1 + giz1 + bhz1);
        float n1 = tanhfast(gin1 + r1 * (an1 + bhn1));
        float h1 = (1.f - z1) * n1 + z1 * hprev1; hprev1 = h1;
        float r2 = sigm(ar2 + gir2 + bhr2);
        float z2 = sigm(az2 + giz2 + bhz2);
        float n2 = tanhfast(gin2 + r2 * (an2 + bhn2));
        float h2 = (1.f - z2) * n2 + z2 * hprev2; hprev2 = h2;
        // h publish: fire-and-forget atomic (performed AT the LLC)
        u32x2 hv = { pk2(h1, h2), (unsigned int)(t + 1) };
        unsigned long long* hdst = hq + (size_t)(t & (HQ_DEPTH - 1)) * 4096
                                      + (size_t)bbh * 256 + w * 16 + dph;
        asm volatile("global_atomic_swap_x2 %0, %1, off sc1"
                     :: "v"(hdst), "v"(hv) : "memory");
        // gi(t+1) prefetch at tail: lands during the next poll
        if (t + 1 < L_SEQ) {
          int d0 = w * 32 + 2 * dph, d1 = d0 + 1;
          const unsigned short* gib = giT + (size_t)(t + 1) * 1536 * 16 + bbh;
          gir1 = bf2f(gib[(size_t)d0 * 16]);
          giz1 = bf2f(gib[(size_t)(512 + d0) * 16]);
          gin1 = bf2f(gib[(size_t)(1024 + d0) * 16]);
          gir2 = bf2f(gib[(size_t)d1 * 16]);
          giz2 = bf2f(gib[(size_t)(512 + d1) * 16]);
          gin2 = bf2f(gib[(size_t)(1024 + d1) * 16]);
        }
      } else {
        const int Tg = dpx >> 3, j0 = (2 * dpx) & 15;
        const int base0 = Tg * PW_T + bbx * 17 + j0;
        float g0 = pb[base0]              + pb[PW_WAVE + base0]              + pb[2*PW_WAVE + base0]              + pb[3*PW_WAVE + base0];
        float g1 = pb[base0 + 1]          + pb[PW_WAVE + base0 + 1]          + pb[2*PW_WAVE + base0 + 1]          + pb[3*PW_WAVE + base0 + 1];
        float x0 = pb[base0 + 2*PW_T]     + pb[PW_WAVE + base0 + 2*PW_T]     + pb[2*PW_WAVE + base0 + 2*PW_T]     + pb[3*PW_WAVE + base0 + 2*PW_T];
        float x1 = pb[base0 + 2*PW_T + 1] + pb[PW_WAVE + base0 + 2*PW_T + 1] + pb[2*PW_WAVE + base0 + 2*PW_T + 1] + pb[3*PW_WAVE + base0 + 2*PW_T + 1];
        float p0 = pb[base0 + 4*PW_T]     + pb[PW_WAVE + base0 + 4*PW_T]     + pb[2*PW_WAVE + base0 + 4*PW_T]     + pb[3*PW_WAVE + base0 + 4*PW_T];
        float p1 = pb[base0 + 4*PW_T + 1] + pb[PW_WAVE + base0 + 4*PW_T + 1] + pb[2*PW_WAVE + base0 + 4*PW_T + 1] + pb[3*PW_WAVE + base0 + 4*PW_T + 1];
        g0 += bgc0; g1 += bgc1; x0 += bxc0; x1 += bxc1; p0 += bpc0; p1 += bpc1;
        u32x4 rec = { pk2(g0, g1), pk2(x0, x1), pk2(p0, p1), (unsigned int)(t + 1) };
        u32x4* rdst = recS + ((size_t)(t & (REC_DEPTH - 1)) * 16 + bbx) * 128 + w * 16 + dpx;
        asm volatile("global_store_dwordx4 %0, %1, off sc0 sc1" :: "v"(rdst), "v"(rec) : "memory");
      }
    }
  } else {
    // ---- consumers: 32 blocks x 4 independent waves = 128 M-slices ----
    const int id = wid - 24;            // 0..31
    const int b = id >> 1, sg = id & 1;
    const int sl = sg * 4 + v;          // slice 0..7 (32 cols each)
    float* Msh = (float*)(smem + v * 32768);  // [256][32] f32
    const int colg = lane & 7, dgs = lane >> 3;
    for (int i = lane * 4; i < 8192; i += 256) *(float4*)&Msh[i] = float4{0.f, 0.f, 0.f, 0.f};
    #pragma unroll 1
    for (int t = 0; t < L_SEQ; ++t) {
      const u32x4* rp = recS + ((size_t)(t & (REC_DEPTH - 1)) * 16 + b) * 128 + 2 * lane;
      const unsigned int tagv = (unsigned int)(t + 1);
      u32x4 r0, r1;
      int spins = 0;
      for (;;) {
        asm volatile(
          "global_load_dwordx4 %0, %2, off sc0 sc1\n\t"
          "global_load_dwordx4 %1, %2, off offset:16 sc0 sc1\n\t"
          "s_waitcnt vmcnt(0)"
          : "=&v"(r0), "=&v"(r1) : "v"(rp) : "memory");
        if (__all((r0.w == tagv) && (r1.w == tagv))) break;
        __builtin_amdgcn_s_sleep(32);  // huge slack (REC ring = 64 steps)
        if (++spins > 2000000) break;
      }
      const int lx = sl * 8 + colg;
      unsigned int xa = (unsigned int)__shfl((int)r0.y, lx);
      unsigned int xb = (unsigned int)__shfl((int)r1.y, lx);
      unsigned int pa = (unsigned int)__shfl((int)r0.z, lx);
      unsigned int pb2 = (unsigned int)__shfl((int)r1.z, lx);
      float xv0 = bf2f(xa), xv1 = bf2f(xa >> 16), xv2 = bf2f(xb), xv3 = bf2f(xb >> 16);
      float r0a = 0, r1a = 0, r2a = 0, r3a = 0;
      #pragma unroll
      for (int ic = 0; ic < 8; ++ic) {
        const int ls = dgs * 8 + ic;
        unsigned int ga = (unsigned int)__shfl((int)r0.x, ls);
        unsigned int gb = (unsigned int)__shfl((int)r1.x, ls);
        float gj[4] = { bf2f(ga), bf2f(ga >> 16), bf2f(gb), bf2f(gb >> 16) };
        int dg = dgs * 32 + ic * 4;
        #pragma unroll
        for (int j = 0; j < 4; ++j) {
          float4* mp = (float4*)&Msh[(dg + j) * 32 + colg * 4];
          float4 m = *mp;
          r0a += gj[j] * m.x; r1a += gj[j] * m.y; r2a += gj[j] * m.z; r3a += gj[j] * m.w;
          m.x += gj[j] * xv0; m.y += gj[j] * xv1; m.z += gj[j] * xv2; m.w += gj[j] * xv3;
          *mp = m;
        }
      }
      #pragma unroll
      for (int off = 8; off < 64; off <<= 1) {
        r0a += __shfl_xor(r0a, off); r1a += __shfl_xor(r1a, off);
        r2a += __shfl_xor(r2a, off); r3a += __shfl_xor(r3a, off);
      }
      if (dgs == 0) {
        float y0 = 0.5f * bf2f(pa) + 0.5f * r0a;
        float y1 = 0.5f * bf2f(pa >> 16) + 0.5f * r1a;
        float y2 = 0.5f * bf2f(pb2) + 0.5f * r2a;
        float y3 = 0.5f * bf2f(pb2 >> 16) + 0.5f * r3a;
        uint2 ou = { pk2(y0, y1), pk2(y2, y3) };
        *(uint2*)(xhat + ((size_t)t * 16 + b) * 256 + sl * 32 + colg * 4) = ou;
      }
    }
  }
}

// ---------------- K3: LayerNorm in place over x_hat rows ----------------
__global__ __launch_bounds__(256) void k_ln(
    unsigned short* xh, const float* __restrict__ g, const float* __restrict__ bta)
{
  int row = blockIdx.x * 4 + (threadIdx.x >> 6);
  int lane = threadIdx.x & 63;
  size_t base = (size_t)row * 256 + lane * 4;
  uint2 raw = *(const uint2*)(xh + base);
  float v0 = bf2f(raw.x), v1 = bf2f(raw.x >> 16), v2 = bf2f(raw.y), v3 = bf2f(raw.y >> 16);
  float s1 = v0 + v1 + v2 + v3;
  float s2 = v0 * v0 + v1 * v1 + v2 * v2 + v3 * v3;
  #pragma unroll
  for (int off = 1; off < 64; off <<= 1) { s1 += __shfl_xor(s1, off); s2 += __shfl_xor(s2, off); }
  float mu = s1 * (1.f / 256.f);
  float var = s2 * (1.f / 256.f) - mu * mu;
  float rs = rsqrtf(var + 1e-5f);
  int c = lane * 4;
  float y0 = (v0 - mu) * rs * g[c] + bta[c];
  float y1 = (v1 - mu) * rs * g[c + 1] + bta[c + 1];
  float y2 = (v2 - mu) * rs * g[c + 2] + bta[c + 2];
  float y3 = (v3 - mu) * rs * g[c + 3] + bta[c + 3];
  uint2 ou = { pk2(y0, y1), pk2(y2, y3) };
  *(uint2*)(xh + base) = ou;
}

// ---------------- K4: logits = LN(x_hat) @ Wo^T + bo -> out (B,L,V) f32 ----------------
__global__ __launch_bounds__(256) void k_logits(
    const unsigned short* __restrict__ ln, const float* __restrict__ Wo,
    const float* __restrict__ bo, float* __restrict__ out)
{
  __shared__ unsigned short As[64 * KPAD];
  __shared__ unsigned short Bs[64 * KPAD];
  __shared__ float Ts[4][16 * 68];   // per-wave 16x64 tile, stride 68
  const int tid = threadIdx.x, lane = tid & 63, wv = tid >> 6;
  const int m0 = blockIdx.y * 64, n0 = blockIdx.x * 64;
  const int sr = tid >> 2, skc = (tid & 3) * 8;
  const unsigned short* asrc = ln + (size_t)(m0 + sr) * 256 + skc;
  const int brow = n0 + sr;
  const bool bok = brow < V_SZ;
  const float* bsrc = Wo + (size_t)(bok ? brow : 0) * 256 + skc;

  f32x4 acc[4];
  #pragma unroll
  for (int i = 0; i < 4; ++i) acc[i] = 0.f;

  for (int ks = 0; ks < 8; ++ks) {
    __syncthreads();
    *(uint4*)&As[sr * KPAD + skc] = *(const uint4*)(asrc + ks * 32);
    uint4 ub = {0u, 0u, 0u, 0u};
    if (bok) {
      float4 q0 = *(const float4*)(bsrc + ks * 32);
      float4 q1 = *(const float4*)(bsrc + ks * 32 + 4);
      ub.x = pk2(q0.x, q0.y); ub.y = pk2(q0.z, q0.w);
      ub.z = pk2(q1.x, q1.y); ub.w = pk2(q1.z, q1.w);
    }
    *(uint4*)&Bs[sr * KPAD + skc] = ub;
    __syncthreads();
    bf16x8 af = *(const bf16x8*)&As[(wv * 16 + (lane & 15)) * KPAD + (lane >> 4) * 8];
    #pragma unroll
    for (int ns = 0; ns < 4; ++ns) {
      bf16x8 bfv = *(const bf16x8*)&Bs[(ns * 16 + (lane & 15)) * KPAD + (lane >> 4) * 8];
      acc[ns] = __builtin_amdgcn_mfma_f32_16x16x32_bf16(af, bfv, acc[ns], 0, 0, 0);
    }
  }
  // stage C tile (bias folded) into this wave's private LDS tile
  {
    const int rbase = 4 * (lane >> 4);
    const int cl = lane & 15;
    #pragma unroll
    for (int ns = 0; ns < 4; ++ns) {
      int col = n0 + cl + ns * 16;
      float bv = (col < V_SZ) ? bo[col] : 0.f;
      #pragma unroll
      for (int rr = 0; rr < 4; ++rr)
        Ts[wv][(rbase + rr) * 68 + cl + ns * 16] = acc[ns][rr] + bv;
    }
  }
  // intra-wave only: ds_write -> ds_read ordering handled by lgkmcnt
  {
    const int rloc = lane >> 2;
    const int c0 = (lane & 3) * 16;
    const int grow = m0 + wv * 16 + rloc;
    if (n0 + c0 + 16 <= V_SZ) {   // V is 16-aligned -> full-chunk guard
      float* dst = out + (size_t)(grow & 15) * ((size_t)L_SEQ * V_SZ)
                       + (size_t)(grow >> 4) * V_SZ + n0 + c0;
      const float* srcT = &Ts[wv][rloc * 68 + c0];
      #pragma unroll
      for (int q = 0; q < 4; ++q)
        *(float4*)(dst + 4 * q) = *(const float4*)(srcT + 4 * q);
    }
  }
}

extern "C" void kernel_launch(void* const* d_in, const int* in_sizes, int n_in,
                              void* d_out, int out_size, void* d_ws, size_t ws_size,
                              hipStream_t stream)
{
  const int*   tokens = (const int*)d_in[0];
  const float* emb    = (const float*)d_in[1];
  const float* Wih    = (const float*)d_in[2];
  const float* Whh    = (const float*)d_in[3];
  const float* bih    = (const float*)d_in[4];
  const float* bhh    = (const float*)d_in[5];
  const float* Wg     = (const float*)d_in[6];
  const float* bg     = (const float*)d_in[7];
  const float* Wx     = (const float*)d_in[8];
  const float* bx     = (const float*)d_in[9];
  const float* Wp     = (const float*)d_in[10];
  const float* bp     = (const float*)d_in[11];
  const float* lng    = (const float*)d_in[12];
  const float* lnb    = (const float*)d_in[13];
  const float* Wo     = (const float*)d_in[14];
  const float* bo     = (const float*)d_in[15];
  float* out = (float*)d_out;

  char* ws = (char*)d_ws;
  size_t off = 0;
  auto take = [&](size_t bytes) -> char* {
    char* p = ws + off;
    off += (bytes + 255) & ~(size_t)255;
    return p;
  };
  unsigned short* giT    = (unsigned short*)take((size_t)1024 * 1536 * 16 * 2);        // 50.33 MB
  u32x4* recS            = (u32x4*)take((size_t)REC_DEPTH * 16 * 128 * 16);            // 2.10 MB ring
  unsigned short* xhat   = (unsigned short*)take((size_t)1024 * 16 * 256 * 2);         // 8.39 MB
  unsigned long long* hq = (unsigned long long*)take((size_t)HQ_DEPTH * 4096 * 8);     // 1.05 MB ring
  if (off > ws_size) return;

  // rings carry embedded step-tags; zero them every call so no stale tag
  // (or 0xAA poison) can false-trigger.
  (void)hipMemsetAsync(recS, 0, (size_t)REC_DEPTH * 16 * 128 * 16, stream);
  (void)hipMemsetAsync(hq, 0, (size_t)HQ_DEPTH * 4096 * 8, stream);

  k_gi<<<dim3(24, 256), 256, 0, stream>>>(tokens, emb, Wih, bih, giT);
  k_scan<<<56, 256, 0, stream>>>(giT, Whh, bhh, Wg, bg, Wx, bx, Wp, bp,
                                 recS, xhat, hq);
  k_ln<<<4096, 256, 0, stream>>>(xhat, lng, lnb);
  k_logits<<<dim3(157, 256), 256, 0, stream>>>(xhat, Wo, bo, out);
}

// Round 16
// 3498.227 us; speedup vs baseline: 1.3915x; 1.0018x over previous
//
#include <hip/hip_runtime.h>

#define L_SEQ 1024
#define B_SZ  16
#define D_SZ  512
#define V_SZ  10000
#define HQ_DEPTH 32    // h ring (32 KB/slot); gh skew <=1, gxp lag << 30
#define REC_DEPTH 64   // record ring; consumer lag << 62
#define PW_T 272       // pscr tile stride in f32 (16 rows x 17)
#define PW_WAVE 1632   // 6 tiles x 272
#define PW_BUF 6528    // 4 waves x 1632

typedef __attribute__((ext_vector_type(8))) short bf16x8;
typedef __attribute__((ext_vector_type(4))) float f32x4;
typedef __attribute__((ext_vector_type(4))) unsigned int u32x4;
typedef __attribute__((ext_vector_type(2))) unsigned int u32x2;

__device__ __forceinline__ float bf2f(unsigned int u) {
  unsigned int x = (u & 0xffffu) << 16;
  return __builtin_bit_cast(float, x);
}
__device__ __forceinline__ unsigned short f2bf(float f) {
  unsigned int x = __builtin_bit_cast(unsigned int, f);
  x += 0x7fffu + ((x >> 16) & 1u);
  return (unsigned short)(x >> 16);
}
__device__ __forceinline__ unsigned int pk2(float lo, float hi) {
  return (unsigned int)f2bf(lo) | ((unsigned int)f2bf(hi) << 16);
}
__device__ __forceinline__ float sigm(float x) { return 1.f / (1.f + __expf(-x)); }
__device__ __forceinline__ float tanhfast(float x) {
  x = fminf(fmaxf(x, -15.f), 15.f);
  float e = __expf(2.f * x);
  return (e - 1.f) / (e + 1.f);
}

#define KPAD 40

// ---------------- K1: gi = gather(emb, tokens) @ W_ih^T + b_ih ----------------
__global__ __launch_bounds__(256) void k_gi(
    const int* __restrict__ tokens, const float* __restrict__ emb,
    const float* __restrict__ Wih, const float* __restrict__ bih,
    unsigned short* __restrict__ giT)
{
  __shared__ unsigned short As[64 * KPAD];
  __shared__ unsigned short Bs[64 * KPAD];
  const int tid = threadIdx.x, lane = tid & 63, wv = tid >> 6;
  const int m0 = blockIdx.y * 64, n0 = blockIdx.x * 64;
  const int sr = tid >> 2, skc = (tid & 3) * 8;
  const int grow = m0 + sr;
  const int tok = tokens[((grow & 15) << 10) + (grow >> 4)];
  const float* asrc = emb + (size_t)tok * 512 + skc;
  const float* bsrc = Wih + (size_t)(n0 + sr) * 512 + skc;

  f32x4 acc[4];
  #pragma unroll
  for (int i = 0; i < 4; ++i) acc[i] = 0.f;

  for (int ks = 0; ks < 16; ++ks) {
    __syncthreads();
    float4 a0 = *(const float4*)(asrc + ks * 32);
    float4 a1 = *(const float4*)(asrc + ks * 32 + 4);
    float4 q0 = *(const float4*)(bsrc + ks * 32);
    float4 q1 = *(const float4*)(bsrc + ks * 32 + 4);
    uint4 ua = { pk2(a0.x, a0.y), pk2(a0.z, a0.w), pk2(a1.x, a1.y), pk2(a1.z, a1.w) };
    uint4 ub = { pk2(q0.x, q0.y), pk2(q0.z, q0.w), pk2(q1.x, q1.y), pk2(q1.z, q1.w) };
    *(uint4*)&As[sr * KPAD + skc] = ua;
    *(uint4*)&Bs[sr * KPAD + skc] = ub;
    __syncthreads();
    bf16x8 af = *(const bf16x8*)&As[(wv * 16 + (lane & 15)) * KPAD + (lane >> 4) * 8];
    #pragma unroll
    for (int ns = 0; ns < 4; ++ns) {
      bf16x8 bfv = *(const bf16x8*)&Bs[(ns * 16 + (lane & 15)) * KPAD + (lane >> 4) * 8];
      acc[ns] = __builtin_amdgcn_mfma_f32_16x16x32_bf16(af, bfv, acc[ns], 0, 0, 0);
    }
  }
  const int mrow = m0 + wv * 16 + 4 * (lane >> 4);
  const int ncol = n0 + (lane & 15);
  #pragma unroll
  for (int ns = 0; ns < 4; ++ns) {
    int col = ncol + ns * 16;
    float bv = bih[col];
    #pragma unroll
    for (int rr = 0; rr < 4; ++rr) {
      int row = mrow + rr;
      giT[((size_t)(row >> 4) * 1536 + col) * 16 + (row & 15)] = f2bf(acc[ns][rr] + bv);
    }
  }
}

#define ISSUE_BATCH(R0,R1,R2,R3,R4,R5,R6,R7,PTR)                       \
  asm volatile(                                                        \
    "global_load_dwordx4 %0, %8, off sc0 sc1\n\t"                      \
    "global_load_dwordx4 %1, %8, off offset:16 sc0 sc1\n\t"            \
    "global_load_dwordx4 %2, %8, off offset:128 sc0 sc1\n\t"           \
    "global_load_dwordx4 %3, %8, off offset:144 sc0 sc1\n\t"           \
    "global_load_dwordx4 %4, %8, off offset:256 sc0 sc1\n\t"           \
    "global_load_dwordx4 %5, %8, off offset:272 sc0 sc1\n\t"           \
    "global_load_dwordx4 %6, %8, off offset:384 sc0 sc1\n\t"           \
    "global_load_dwordx4 %7, %8, off offset:400 sc0 sc1"               \
    : "=&v"(R0), "=&v"(R1), "=&v"(R2), "=&v"(R3),                      \
      "=&v"(R4), "=&v"(R5), "=&v"(R6), "=&v"(R7)                       \
    : "v"(PTR) : "memory")

#define TAGS_OK(R0,R1,R2,R3,R4,R5,R6,R7,TV)                            \
  ((R0.y == TV) & (R0.w == TV) & (R1.y == TV) & (R1.w == TV) &         \
   (R2.y == TV) & (R2.w == TV) & (R3.y == TV) & (R3.w == TV) &         \
   (R4.y == TV) & (R4.w == TV) & (R5.y == TV) & (R5.w == TV) &         \
   (R6.y == TV) & (R6.w == TV) & (R7.y == TV) & (R7.w == TV))

// ---------------- K2: persistent fused scan, K-split tagged exchange ----------------
// R10/R12 structure. Producer weight fragments live in REGISTERS (24 x bf16x8
// per wave = its K-quarter of all 6 tiles), loaded once from global at init.
__global__ __launch_bounds__(256) void k_scan(
    const unsigned short* __restrict__ giT,
    const float* __restrict__ Whh, const float* __restrict__ bhh,
    const float* __restrict__ Wg, const float* __restrict__ bg,
    const float* __restrict__ Wx, const float* __restrict__ bx,
    const float* __restrict__ Wp, const float* __restrict__ bp,
    u32x4* __restrict__ recS, unsigned short* __restrict__ xhat,
    unsigned long long* __restrict__ hq)
{
  __shared__ char smem[131072];
  const int tid = threadIdx.x;
  const int lane = tid & 63, v = tid >> 6;
  const int wid = blockIdx.x;

  if (wid < 24) {
    const bool isGH = (wid < 16);
    const int w = isGH ? wid : (wid - 16);
    float* pscr = (float*)smem;          // 2 bufs x 4 waves x 6 x 272 f32 = 52224 B

    const int b_ = lane & 15, hi = lane >> 4;
    const int bbh = tid & 15, dph = tid >> 4;   // gh pointwise mapping
    const int bbx = tid >> 4, dpx = tid & 15;   // gxp pointwise mapping

    // ---- register-resident weight fragments: wave v's K-quarter of 6 tiles ----
    bf16x8 wreg[6][4];
    #pragma unroll
    for (int T = 0; T < 6; ++T) {
      const int gate = T >> 1;
      const int drow = w * 32 + (T & 1) * 16 + b_;
      const float* src;
      if (isGH) src = Whh + ((size_t)gate * 512 + drow) * 512;
      else      src = ((gate == 0) ? Wg : (gate == 1) ? Wx : Wp) + (size_t)drow * 512;
      const float* p = src + (size_t)(4 * v) * 32 + hi * 8;
      #pragma unroll
      for (int kkl = 0; kkl < 4; ++kkl) {
        float4 p0 = *(const float4*)(p + kkl * 32);
        float4 p1 = *(const float4*)(p + kkl * 32 + 4);
        u32x4 u = { pk2(p0.x, p0.y), pk2(p0.z, p0.w), pk2(p1.x, p1.y), pk2(p1.z, p1.w) };
        wreg[T][kkl] = __builtin_bit_cast(bf16x8, u);
      }
    }

    float bhr1 = 0, bhz1 = 0, bhn1 = 0, bhr2 = 0, bhz2 = 0, bhn2 = 0;
    float bgc0 = 0, bgc1 = 0, bxc0 = 0, bxc1 = 0, bpc0 = 0, bpc1 = 0;
    float hprev1 = 0.f, hprev2 = 0.f;
    if (isGH) {
      int d0 = w * 32 + 2 * dph, d1 = d0 + 1;
      bhr1 = bhh[d0]; bhz1 = bhh[512 + d0]; bhn1 = bhh[1024 + d0];
      bhr2 = bhh[d1]; bhz2 = bhh[512 + d1]; bhn2 = bhh[1024 + d1];
    } else {
      int d0 = w * 32 + 2 * dpx, d1 = d0 + 1;
      bgc0 = bg[d0]; bgc1 = bg[d1];
      bxc0 = bx[d0]; bxc1 = bx[d1];
      bpc0 = bp[d0]; bpc1 = bp[d1];
    }

    float gir1 = 0, giz1 = 0, gin1 = 0, gir2 = 0, giz2 = 0, gin2 = 0;
    if (isGH) {
      int d0 = w * 32 + 2 * dph, d1 = d0 + 1;
      const unsigned short* gib = giT + bbh;
      gir1 = bf2f(gib[(size_t)d0 * 16]);
      giz1 = bf2f(gib[(size_t)(512 + d0) * 16]);
      gin1 = bf2f(gib[(size_t)(1024 + d0) * 16]);
      gir2 = bf2f(gib[(size_t)d1 * 16]);
      giz2 = bf2f(gib[(size_t)(512 + d1) * 16]);
      gin2 = bf2f(gib[(size_t)(1024 + d1) * 16]);
    }

    const size_t pofs = (size_t)b_ * 256 + 64 * v + 4 * hi;

    #pragma unroll 1
    for (int t = 0; t < L_SEQ; ++t) {
      const int pt = isGH ? (t - 1) : t;   // h step consumed this iteration
      f32x4 pacc[6];
      #pragma unroll
      for (int i = 0; i < 6; ++i) pacc[i] = 0.f;

      if (pt >= 0) {
        const unsigned long long* hsrc = hq + (size_t)(pt & (HQ_DEPTH - 1)) * 4096 + pofs;
        const unsigned int tv = (unsigned int)(pt + 1);
        u32x4 q0, q1, q2, q3, q4, q5, q6, q7;
        int spins = 0;
        for (;;) {
          ISSUE_BATCH(q0, q1, q2, q3, q4, q5, q6, q7, hsrc);
          asm volatile("s_waitcnt vmcnt(0)" ::: "memory");
          if (__all(TAGS_OK(q0, q1, q2, q3, q4, q5, q6, q7, tv))) break;
          if (!isGH) __builtin_amdgcn_s_sleep(16);  // gxp: a full step of slack
          if (++spins > 2000000) break;
        }
        u32x4 f0 = { q0.x, q0.z, q1.x, q1.z };
        u32x4 f1 = { q2.x, q2.z, q3.x, q3.z };
        u32x4 f2 = { q4.x, q4.z, q5.x, q5.z };
        u32x4 f3 = { q6.x, q6.z, q7.x, q7.z };
        bf16x8 a0 = __builtin_bit_cast(bf16x8, f0);
        bf16x8 a1 = __builtin_bit_cast(bf16x8, f1);
        bf16x8 a2 = __builtin_bit_cast(bf16x8, f2);
        bf16x8 a3 = __builtin_bit_cast(bf16x8, f3);
        #pragma unroll
        for (int T = 0; T < 6; ++T) {
          pacc[T] = __builtin_amdgcn_mfma_f32_16x16x32_bf16(a0, wreg[T][0], pacc[T], 0, 0, 0);
          pacc[T] = __builtin_amdgcn_mfma_f32_16x16x32_bf16(a1, wreg[T][1], pacc[T], 0, 0, 0);
          pacc[T] = __builtin_amdgcn_mfma_f32_16x16x32_bf16(a2, wreg[T][2], pacc[T], 0, 0, 0);
          pacc[T] = __builtin_amdgcn_mfma_f32_16x16x32_bf16(a3, wreg[T][3], pacc[T], 0, 0, 0);
        }
      }

      {
        float* pw = pscr + (size_t)(t & 1) * PW_BUF + (size_t)v * PW_WAVE;
        #pragma unroll
        for (int T = 0; T < 6; ++T) {
          #pragma unroll
          for (int rr = 0; rr < 4; ++rr)
            pw[T * PW_T + (4 * hi + rr) * 17 + b_] = pacc[T][rr];
        }
      }
      __syncthreads();   // single per-step barrier; nothing fresh in flight here

      const float* pb = pscr + (size_t)(t & 1) * PW_BUF;
      if (isGH) {
        const int Tr = dph >> 3, j0 = (2 * dph) & 15;
        const int base0 = Tr * PW_T + bbh * 17 + j0;
        float ar1 = pb[base0]              + pb[PW_WAVE + base0]              + pb[2*PW_WAVE + base0]              + pb[3*PW_WAVE + base0];
        float ar2 = pb[base0 + 1]          + pb[PW_WAVE + base0 + 1]          + pb[2*PW_WAVE + base0 + 1]          + pb[3*PW_WAVE + base0 + 1];
        float az1 = pb[base0 + 2*PW_T]     + pb[PW_WAVE + base0 + 2*PW_T]     + pb[2*PW_WAVE + base0 + 2*PW_T]     + pb[3*PW_WAVE + base0 + 2*PW_T];
        float az2 = pb[base0 + 2*PW_T + 1] + pb[PW_WAVE + base0 + 2*PW_T + 1] + pb[2*PW_WAVE + base0 + 2*PW_T + 1] + pb[3*PW_WAVE + base0 + 2*PW_T + 1];
        float an1 = pb[base0 + 4*PW_T]     + pb[PW_WAVE + base0 + 4*PW_T]     + pb[2*PW_WAVE + base0 + 4*PW_T]     + pb[3*PW_WAVE + base0 + 4*PW_T];
        float an2 = pb[base0 + 4*PW_T + 1] + pb[PW_WAVE + base0 + 4*PW_T + 1] + pb[2*PW_WAVE + base0 + 4*PW_T + 1] + pb[3*PW_WAVE + base0 + 4*PW_T + 1];
        float r1 = sigm(ar1 + gir1 + bhr1);
        float z1 = sigm(az1 + giz1 + bhz1);
        float n1 = tanhfast(gin1 + r1 * (an1 + bhn1));
        float h1 = (1.f - z1) * n1 + z1 * hprev1; hprev1 = h1;
        float r2 = sigm(ar2 + gir2 + bhr2);
        float z2 = sigm(az2 + giz2 + bhz2);
        float n2 = tanhfast(gin2 + r2 * (an2 + bhn2));
        float h2 = (1.f - z2) * n2 + z2 * hprev2; hprev2 = h2;
        // h publish: fire-and-forget atomic (performed AT the LLC)
        u32x2 hv = { pk2(h1, h2), (unsigned int)(t + 1) };
        unsigned long long* hdst = hq + (size_t)(t & (HQ_DEPTH - 1)) * 4096
                                      + (size_t)bbh * 256 + w * 16 + dph;
        asm volatile("global_atomic_swap_x2 %0, %1, off sc1"
                     :: "v"(hdst), "v"(hv) : "memory");
        // gi(t+1) prefetch at tail: lands during the next poll
        if (t + 1 < L_SEQ) {
          int d0 = w * 32 + 2 * dph, d1 = d0 + 1;
          const unsigned short* gib = giT + (size_t)(t + 1) * 1536 * 16 + bbh;
          gir1 = bf2f(gib[(size_t)d0 * 16]);
          giz1 = bf2f(gib[(size_t)(512 + d0) * 16]);
          gin1 = bf2f(gib[(size_t)(1024 + d0) * 16]);
          gir2 = bf2f(gib[(size_t)d1 * 16]);
          giz2 = bf2f(gib[(size_t)(512 + d1) * 16]);
          gin2 = bf2f(gib[(size_t)(1024 + d1) * 16]);
        }
      } else {
        const int Tg = dpx >> 3, j0 = (2 * dpx) & 15;
        const int base0 = Tg * PW_T + bbx * 17 + j0;
        float g0 = pb[base0]              + pb[PW_WAVE + base0]              + pb[2*PW_WAVE + base0]              + pb[3*PW_WAVE + base0];
        float g1 = pb[base0 + 1]          + pb[PW_WAVE + base0 + 1]          + pb[2*PW_WAVE + base0 + 1]          + pb[3*PW_WAVE + base0 + 1];
        float x0 = pb[base0 + 2*PW_T]     + pb[PW_WAVE + base0 + 2*PW_T]     + pb[2*PW_WAVE + base0 + 2*PW_T]     + pb[3*PW_WAVE + base0 + 2*PW_T];
        float x1 = pb[base0 + 2*PW_T + 1] + pb[PW_WAVE + base0 + 2*PW_T + 1] + pb[2*PW_WAVE + base0 + 2*PW_T + 1] + pb[3*PW_WAVE + base0 + 2*PW_T + 1];
        float p0 = pb[base0 + 4*PW_T]     + pb[PW_WAVE + base0 + 4*PW_T]     + pb[2*PW_WAVE + base0 + 4*PW_T]     + pb[3*PW_WAVE + base0 + 4*PW_T];
        float p1 = pb[base0 + 4*PW_T + 1] + pb[PW_WAVE + base0 + 4*PW_T + 1] + pb[2*PW_WAVE + base0 + 4*PW_T + 1] + pb[3*PW_WAVE + base0 + 4*PW_T + 1];
        g0 += bgc0; g1 += bgc1; x0 += bxc0; x1 += bxc1; p0 += bpc0; p1 += bpc1;
        u32x4 rec = { pk2(g0, g1), pk2(x0, x1), pk2(p0, p1), (unsigned int)(t + 1) };
        u32x4* rdst = recS + ((size_t)(t & (REC_DEPTH - 1)) * 16 + bbx) * 128 + w * 16 + dpx;
        asm volatile("global_store_dwordx4 %0, %1, off sc0 sc1" :: "v"(rdst), "v"(rec) : "memory");
      }
    }
  } else {
    // ---- consumers: 32 blocks x 4 independent waves = 128 M-slices ----
    const int id = wid - 24;            // 0..31
    const int b = id >> 1, sg = id & 1;
    const int sl = sg * 4 + v;          // slice 0..7 (32 cols each)
    float* Msh = (float*)(smem + v * 32768);  // [256][32] f32
    const int colg = lane & 7, dgs = lane >> 3;
    for (int i = lane * 4; i < 8192; i += 256) *(float4*)&Msh[i] = float4{0.f, 0.f, 0.f, 0.f};
    #pragma unroll 1
    for (int t = 0; t < L_SEQ; ++t) {
      const u32x4* rp = recS + ((size_t)(t & (REC_DEPTH - 1)) * 16 + b) * 128 + 2 * lane;
      const unsigned int tagv = (unsigned int)(t + 1);
      u32x4 r0, r1;
      int spins = 0;
      for (;;) {
        asm volatile(
          "global_load_dwordx4 %0, %2, off sc0 sc1\n\t"
          "global_load_dwordx4 %1, %2, off offset:16 sc0 sc1\n\t"
          "s_waitcnt vmcnt(0)"
          : "=&v"(r0), "=&v"(r1) : "v"(rp) : "memory");
        if (__all((r0.w == tagv) && (r1.w == tagv))) break;
        __builtin_amdgcn_s_sleep(32);  // huge slack (REC ring = 64 steps)
        if (++spins > 2000000) break;
      }
      const int lx = sl * 8 + colg;
      unsigned int xa = (unsigned int)__shfl((int)r0.y, lx);
      unsigned int xb = (unsigned int)__shfl((int)r1.y, lx);
      unsigned int pa = (unsigned int)__shfl((int)r0.z, lx);
      unsigned int pb2 = (unsigned int)__shfl((int)r1.z, lx);
      float xv0 = bf2f(xa), xv1 = bf2f(xa >> 16), xv2 = bf2f(xb), xv3 = bf2f(xb >> 16);
      float r0a = 0, r1a = 0, r2a = 0, r3a = 0;
      #pragma unroll
      for (int ic = 0; ic < 8; ++ic) {
        const int ls = dgs * 8 + ic;
        unsigned int ga = (unsigned int)__shfl((int)r0.x, ls);
        unsigned int gb = (unsigned int)__shfl((int)r1.x, ls);
        float gj[4] = { bf2f(ga), bf2f(ga >> 16), bf2f(gb), bf2f(gb >> 16) };
        int dg = dgs * 32 + ic * 4;
        #pragma unroll
        for (int j = 0; j < 4; ++j) {
          float4* mp = (float4*)&Msh[(dg + j) * 32 + colg * 4];
          float4 m = *mp;
          r0a += gj[j] * m.x; r1a += gj[j] * m.y; r2a += gj[j] * m.z; r3a += gj[j] * m.w;
          m.x += gj[j] * xv0; m.y += gj[j] * xv1; m.z += gj[j] * xv2; m.w += gj[j] * xv3;
          *mp = m;
        }
      }
      #pragma unroll
      for (int off = 8; off < 64; off <<= 1) {
        r0a += __shfl_xor(r0a, off); r1a += __shfl_xor(r1a, off);
        r2a += __shfl_xor(r2a, off); r3a += __shfl_xor(r3a, off);
      }
      if (dgs == 0) {
        float y0 = 0.5f * bf2f(pa) + 0.5f * r0a;
        float y1 = 0.5f * bf2f(pa >> 16) + 0.5f * r1a;
        float y2 = 0.5f * bf2f(pb2) + 0.5f * r2a;
        float y3 = 0.5f * bf2f(pb2 >> 16) + 0.5f * r3a;
        uint2 ou = { pk2(y0, y1), pk2(y2, y3) };
        *(uint2*)(xhat + ((size_t)t * 16 + b) * 256 + sl * 32 + colg * 4) = ou;
      }
    }
  }
}

// ---------------- K3: LayerNorm in place over x_hat rows ----------------
__global__ __launch_bounds__(256) void k_ln(
    unsigned short* xh, const float* __restrict__ g, const float* __restrict__ bta)
{
  int row = blockIdx.x * 4 + (threadIdx.x >> 6);
  int lane = threadIdx.x & 63;
  size_t base = (size_t)row * 256 + lane * 4;
  uint2 raw = *(const uint2*)(xh + base);
  float v0 = bf2f(raw.x), v1 = bf2f(raw.x >> 16), v2 = bf2f(raw.y), v3 = bf2f(raw.y >> 16);
  float s1 = v0 + v1 + v2 + v3;
  float s2 = v0 * v0 + v1 * v1 + v2 * v2 + v3 * v3;
  #pragma unroll
  for (int off = 1; off < 64; off <<= 1) { s1 += __shfl_xor(s1, off); s2 += __shfl_xor(s2, off); }
  float mu = s1 * (1.f / 256.f);
  float var = s2 * (1.f / 256.f) - mu * mu;
  float rs = rsqrtf(var + 1e-5f);
  int c = lane * 4;
  float y0 = (v0 - mu) * rs * g[c] + bta[c];
  float y1 = (v1 - mu) * rs * g[c + 1] + bta[c + 1];
  float y2 = (v2 - mu) * rs * g[c + 2] + bta[c + 2];
  float y3 = (v3 - mu) * rs * g[c + 3] + bta[c + 3];
  uint2 ou = { pk2(y0, y1), pk2(y2, y3) };
  *(uint2*)(xh + base) = ou;
}

// ---------------- K4: logits = LN(x_hat) @ Wo^T + bo -> out (B,L,V) f32 ----------------
__global__ __launch_bounds__(256) void k_logits(
    const unsigned short* __restrict__ ln, const float* __restrict__ Wo,
    const float* __restrict__ bo, float* __restrict__ out)
{
  __shared__ unsigned short As[64 * KPAD];
  __shared__ unsigned short Bs[64 * KPAD];
  __shared__ float Ts[4][16 * 68];   // per-wave 16x64 tile, stride 68
  const int tid = threadIdx.x, lane = tid & 63, wv = tid >> 6;
  const int m0 = blockIdx.y * 64, n0 = blockIdx.x * 64;
  const int sr = tid >> 2, skc = (tid & 3) * 8;
  const unsigned short* asrc = ln + (size_t)(m0 + sr) * 256 + skc;
  const int brow = n0 + sr;
  const bool bok = brow < V_SZ;
  const float* bsrc = Wo + (size_t)(bok ? brow : 0) * 256 + skc;

  f32x4 acc[4];
  #pragma unroll
  for (int i = 0; i < 4; ++i) acc[i] = 0.f;

  for (int ks = 0; ks < 8; ++ks) {
    __syncthreads();
    *(uint4*)&As[sr * KPAD + skc] = *(const uint4*)(asrc + ks * 32);
    uint4 ub = {0u, 0u, 0u, 0u};
    if (bok) {
      float4 q0 = *(const float4*)(bsrc + ks * 32);
      float4 q1 = *(const float4*)(bsrc + ks * 32 + 4);
      ub.x = pk2(q0.x, q0.y); ub.y = pk2(q0.z, q0.w);
      ub.z = pk2(q1.x, q1.y); ub.w = pk2(q1.z, q1.w);
    }
    *(uint4*)&Bs[sr * KPAD + skc] = ub;
    __syncthreads();
    bf16x8 af = *(const bf16x8*)&As[(wv * 16 + (lane & 15)) * KPAD + (lane >> 4) * 8];
    #pragma unroll
    for (int ns = 0; ns < 4; ++ns) {
      bf16x8 bfv = *(const bf16x8*)&Bs[(ns * 16 + (lane & 15)) * KPAD + (lane >> 4) * 8];
      acc[ns] = __builtin_amdgcn_mfma_f32_16x16x32_bf16(af, bfv, acc[ns], 0, 0, 0);
    }
  }
  // stage C tile (bias folded) into this wave's private LDS tile
  {
    const int rbase = 4 * (lane >> 4);
    const int cl = lane & 15;
    #pragma unroll
    for (int ns = 0; ns < 4; ++ns) {
      int col = n0 + cl + ns * 16;
      float bv = (col < V_SZ) ? bo[col] : 0.f;
      #pragma unroll
      for (int rr = 0; rr < 4; ++rr)
        Ts[wv][(rbase + rr) * 68 + cl + ns * 16] = acc[ns][rr] + bv;
    }
  }
  // intra-wave only: ds_write -> ds_read ordering handled by lgkmcnt
  {
    const int rloc = lane >> 2;
    const int c0 = (lane & 3) * 16;
    const int grow = m0 + wv * 16 + rloc;
    if (n0 + c0 + 16 <= V_SZ) {   // V is 16-aligned -> full-chunk guard
      float* dst = out + (size_t)(grow & 15) * ((size_t)L_SEQ * V_SZ)
                       + (size_t)(grow >> 4) * V_SZ + n0 + c0;
      const float* srcT = &Ts[wv][rloc * 68 + c0];
      #pragma unroll
      for (int q = 0; q < 4; ++q)
        *(float4*)(dst + 4 * q) = *(const float4*)(srcT + 4 * q);
    }
  }
}

extern "C" void kernel_launch(void* const* d_in, const int* in_sizes, int n_in,
                              void* d_out, int out_size, void* d_ws, size_t ws_size,
                              hipStream_t stream)
{
  const int*   tokens = (const int*)d_in[0];
  const float* emb    = (const float*)d_in[1];
  const float* Wih    = (const float*)d_in[2];
  const float* Whh    = (const float*)d_in[3];
  const float* bih    = (const float*)d_in[4];
  const float* bhh    = (const float*)d_in[5];
  const float* Wg     = (const float*)d_in[6];
  const float* bg     = (const float*)d_in[7];
  const float* Wx     = (const float*)d_in[8];
  const float* bx     = (const float*)d_in[9];
  const float* Wp     = (const float*)d_in[10];
  const float* bp     = (const float*)d_in[11];
  const float* lng    = (const float*)d_in[12];
  const float* lnb    = (const float*)d_in[13];
  const float* Wo     = (const float*)d_in[14];
  const float* bo     = (const float*)d_in[15];
  float* out = (float*)d_out;

  char* ws = (char*)d_ws;
  size_t off = 0;
  auto take = [&](size_t bytes) -> char* {
    char* p = ws + off;
    off += (bytes + 255) & ~(size_t)255;
    return p;
  };
  unsigned short* giT    = (unsigned short*)take((size_t)1024 * 1536 * 16 * 2);        // 50.33 MB
  u32x4* recS            = (u32x4*)take((size_t)REC_DEPTH * 16 * 128 * 16);            // 2.10 MB ring
  unsigned short* xhat   = (unsigned short*)take((size_t)1024 * 16 * 256 * 2);         // 8.39 MB
  unsigned long long* hq = (unsigned long long*)take((size_t)HQ_DEPTH * 4096 * 8);     // 1.05 MB ring
  if (off > ws_size) return;

  // rings carry embedded step-tags; zero them every call so no stale tag
  // (or 0xAA poison) can false-trigger.
  (void)hipMemsetAsync(recS, 0, (size_t)REC_DEPTH * 16 * 128 * 16, stream);
  (void)hipMemsetAsync(hq, 0, (size_t)HQ_DEPTH * 4096 * 8, stream);

  k_gi<<<dim3(24, 256), 256, 0, stream>>>(tokens, emb, Wih, bih, giT);
  k_scan<<<56, 256, 0, stream>>>(giT, Whh, bhh, Wg, bg, Wx, bx, Wp, bp,
                                 recS, xhat, hq);
  k_ln<<<4096, 256, 0, stream>>>(xhat, lng, lnb);
  k_logits<<<dim3(157, 256), 256, 0, stream>>>(xhat, Wo, bo, out);
}